// Round 9
// baseline (204.994 us; speedup 1.0000x reference)
//
#include <hip/hip_runtime.h>
#include <hip/hip_bf16.h>
#include <math.h>

#define DEVINL __device__ __forceinline__

typedef short short8 __attribute__((ext_vector_type(8)));
typedef float f32x4 __attribute__((ext_vector_type(4)));

DEVINL unsigned short f2bf(float f) {
    union { float f; unsigned int u; } c; c.f = f;
    unsigned int u = c.u;
    return (unsigned short)((u + 0x7fffu + ((u >> 16) & 1u)) >> 16);
}

DEVINL unsigned int packbf2(float a, float b) {
    union { __hip_bfloat162 h; unsigned int u; } c;
    c.h = __float22bfloat162_rn(make_float2(a, b));
    return c.u;  // a low 16, b high 16
}

// Closed-form quadratic B-spline expansion, uniform extended grid
// (knots t_i=(i-2)*(2/3)-1): u=1.5x+3.5, j=floor(u), t=u-j.
// Frag = bf16x8 [relu(x), b0..b4, 0, 0].
DEVINL uint4 expand_frag(float v) {
    float relu = fmaxf(v, 0.f);
    float u = fmaf(v, 1.5f, 3.5f);
    float fj = floorf(u);
    int j = (int)fj;
    float t = u - fj;
    float omt = 1.f - t;
    float v2 = 0.5f * omt * omt;
    float v1 = fmaf(t, omt, 0.5f);
    float v0 = 0.5f * t * t;
    float b[5];
#pragma unroll
    for (int i = 0; i < 5; ++i)
        b[i] = (i == j) ? v0 : (i == j - 1) ? v1 : (i == j - 2) ? v2 : 0.f;
    uint4 r;
    r.x = packbf2(relu, b[0]);
    r.y = packbf2(b[1], b[2]);
    r.z = packbf2(b[3], b[4]);
    r.w = 0u;
    return r;
}

// ---- weight prep: one MFMA B-fragment (8 bf16) per thread ----
// wf[(((c*NTT+nt)*4+ks)*64+lane)*8+j] = W[k][o], k=ks*32+(lane>>4)*8+j,
// tap = ks*4+(lane>>4), s=j: s==0->bw, 1..5->sw*sc, 6,7->0.
DEVINL void prep_frag(int fi, int F, int NTT, const float* __restrict__ bw,
                      const float* __restrict__ sw, const float* __restrict__ sc,
                      unsigned short* __restrict__ wf) {
    int lane = fi & 63;
    int t = fi >> 6;        // (c*NTT+nt)*4 + ks
    int ks = t & 3;
    int t2 = t >> 2;
    int nt = t2 % NTT;
    int c = t2 / NTT;
    int tap = ks * 4 + (lane >> 4);
    int f = c * 16 + tap;
    int o = nt * 16 + (lane & 15);
    float scv = sc[o * F + f];
    float b = bw[o * F + f];
    float s0 = sw[(o * F + f) * 5 + 0] * scv;
    float s1 = sw[(o * F + f) * 5 + 1] * scv;
    float s2 = sw[(o * F + f) * 5 + 2] * scv;
    float s3 = sw[(o * F + f) * 5 + 3] * scv;
    float s4 = sw[(o * F + f) * 5 + 4] * scv;
    uint4 r;
    r.x = packbf2(b, s0);
    r.y = packbf2(s1, s2);
    r.z = packbf2(s3, s4);
    r.w = 0u;
    *(uint4*)&wf[(size_t)fi * 8] = r;
}

__global__ __launch_bounds__(256) void prep_all(
    const float* __restrict__ bw1, const float* __restrict__ sw1, const float* __restrict__ sc1,
    const float* __restrict__ bw2, const float* __restrict__ sw2, const float* __restrict__ sc2,
    const float* __restrict__ bw3, const float* __restrict__ sw3, const float* __restrict__ sc3,
    const float* __restrict__ bw4, const float* __restrict__ sw4, const float* __restrict__ sc4,
    unsigned short* __restrict__ wf1, unsigned short* __restrict__ wf2,
    unsigned short* __restrict__ wf3, unsigned short* __restrict__ wf4) {
    int fi = blockIdx.x * 256 + threadIdx.x;
    const int N1 = 3 * 32 * 16;           // 1536 frags
    const int N2 = 32 * 64 * 16;          // 32768
    const int N3 = 64 * 128 * 16;         // 131072
    const int N4 = 128 * 128 * 16;        // 262144
    if (fi < N1) prep_frag(fi, 48, 2, bw1, sw1, sc1, wf1);
    else if (fi < N1 + N2) prep_frag(fi - N1, 512, 4, bw2, sw2, sc2, wf2);
    else if (fi < N1 + N2 + N3) prep_frag(fi - N1 - N2, 1024, 8, bw3, sw3, sc3, wf3);
    else if (fi < N1 + N2 + N3 + N4) prep_frag(fi - N1 - N2 - N3, 2048, 8, bw4, sw4, sc4, wf4);
}

// ---- fused KAN conv: A expanded in LDS, B streamed global->VGPR ----
// Per phase: expand UB channels' input tiles into LDS (once per element) ->
// barrier -> MFMA loop with bf fragments loaded DIRECTLY from wf (L2-resident,
// coalesced 16B/lane) -> barrier. Operand feed: A via LDS port, B via L2 port
// (parallel). No gload_lds, no stage drain. BN scale/shift derived in-kernel
// from partials; NOT applied to padding zeros (pad taps read slot 0 =
// expansion of v=0).
template <int CIN, int COUTT, int NSP, int HOUT, int WOUT, int WM, int WN, int MT,
          int CPS, int UB, bool HASBN, int BNS, int NBN, bool SPLITOUT, int RPAD>
__global__ __launch_bounds__(256) void kan_conv_fused(
    const float* __restrict__ in, const unsigned short* __restrict__ wf,
    const float* __restrict__ part, const float* __restrict__ gamma,
    const float* __restrict__ beta, float* __restrict__ out) {
    constexpr int HIN = HOUT * 2, WIN = WOUT * 2, W2 = WOUT;
    constexpr int COUT = COUTT / NSP;       // this block's N extent
    constexpr int NTT = COUTT / 16;
    constexpr int NT = COUT / 16;
    constexpr int NTW = NT / WN;
    constexpr int BM = WM * MT * 16;
    constexpr int IMG_POS = HOUT * WOUT;
    constexpr int NIMG = BM / IMG_POS;
    constexpr int RS = WIN + RPAD;
    constexpr int IMG_STRIDE = HIN * RS + 1;
    constexpr int ASLOTS = NIMG * IMG_STRIDE + 1;  // slot 0 = pad frag
    constexpr int M_TOT = 512 * IMG_POS;
    constexpr int EV = NIMG * HIN * WIN;
    constexpr int EITER = (EV + 255) / 256;
    static_assert(WM * WN == 4, "4 waves");
    static_assert(CPS % UB == 0, "UB divides CPS");

    __shared__ uint4 A_e[UB][ASLOTS];

    const int tid = threadIdx.x;
    const int lane = tid & 63;
    const int w = tid >> 6;
    const int wm = w % WM;
    const int wn = w / WM;
    const int g = lane >> 4;        // kw
    const int r16 = lane & 15;
    const int m0 = blockIdx.x * BM;
    const int b0 = m0 / IMG_POS;
    const int nh = (NSP > 1) ? ((int)blockIdx.y % NSP) : 0;
    const int kslice = (NSP > 1) ? ((int)blockIdx.y / NSP) : (SPLITOUT ? (int)blockIdx.y : 0);
    const int c0 = SPLITOUT ? kslice * CPS : 0;

    // Per-mt fragment geometry (channel-invariant).
    int aoff[MT];
    int vmask = 0;
#pragma unroll
    for (int mt = 0; mt < MT; ++mt) {
        int p = (wm * MT + mt) * 16 + r16;
        int m = m0 + p;
        int ow = m % WOUT;
        int oh = (m / WOUT) % HOUT;
        int bl = p / IMG_POS;
        int iw = 2 * ow - 1 + g;
        bool iv = (iw >= 0) && (iw < WIN);
        aoff[mt] = 1 + bl * IMG_STRIDE + (2 * oh) * RS + (iw & 1) * W2 + (iw >> 1);
#pragma unroll
        for (int ks = 0; ks < 4; ++ks) {
            bool vv = iv && !(oh == 0 && ks == 0) && !(oh == HOUT - 1 && ks == 3);
            vmask |= (vv ? 1 : 0) << (mt * 4 + ks);
        }
    }

    if (tid < UB) A_e[tid][0] = expand_frag(0.f);  // pad slots, covered by 1st barrier

    f32x4 acc[MT][NTW];
#pragma unroll
    for (int mt = 0; mt < MT; ++mt)
#pragma unroll
        for (int n = 0; n < NTW; ++n) acc[mt][n] = f32x4{0.f, 0.f, 0.f, 0.f};

    for (int cc = 0; cc < CPS; cc += UB) {
        // (1) expand UB channels' tiles into LDS (once per element); BN folded
#pragma unroll
        for (int u = 0; u < UB; ++u) {
            const int ch = c0 + cc + u;
            float bsc = 1.f, bsh = 0.f;
            if (HASBN) {  // uniform scalar reduction of BN partials
                float sm = 0.f, s2 = 0.f;
#pragma unroll 4
                for (int s = 0; s < BNS; ++s) {
                    sm += part[(ch * BNS + s) * 2];
                    s2 += part[(ch * BNS + s) * 2 + 1];
                }
                const float invN = 1.f / (float)NBN;
                float mean = sm * invN;
                float var = s2 * invN - mean * mean;
                float rs = rsqrtf(var + 1e-5f);
                bsc = gamma[ch] * rs;
                bsh = beta[ch] - mean * bsc;
            }
#pragma unroll
            for (int ii = 0; ii < EITER; ++ii) {
                int e = tid + ii * 256;
                if ((EV % 256 == 0) || e < EV) {
                    int bl = e / (HIN * WIN);
                    int r = e - bl * (HIN * WIN);
                    int ih = r / WIN;
                    int iw = r - ih * WIN;
                    float v = in[(((size_t)(b0 + bl) * CIN + ch) * HIN + ih) * WIN + iw];
                    if (HASBN) v = fmaf(v, bsc, bsh);
                    A_e[u][1 + bl * IMG_STRIDE + ih * RS + (iw & 1) * W2 + (iw >> 1)] = expand_frag(v);
                }
            }
        }
        __syncthreads();  // A ds_writes visible
        // (2) MFMA: af from LDS, bf streamed from global (L2) per fragment
#pragma unroll
        for (int u = 0; u < UB; ++u) {
            const int ch = c0 + cc + u;
            // per-channel frag block = NTT*4*64*8 = NTT*2048 ushorts
            const unsigned short* wfc = wf + (((size_t)ch * NTT + nh * NT) << 11);
#pragma unroll
            for (int ks = 0; ks < 4; ++ks) {
                short8 bf[NTW];
#pragma unroll
                for (int n = 0; n < NTW; ++n)
                    bf[n] = *(const short8*)&wfc[((((wn * NTW + n) << 2) + ks) << 9) + (lane << 3)];
#pragma unroll
                for (int mt = 0; mt < MT; ++mt) {
                    int slot = ((vmask >> (mt * 4 + ks)) & 1) ? (aoff[mt] + (ks - 1) * RS) : 0;
                    short8 af = *(const short8*)&A_e[u][slot];
#pragma unroll
                    for (int n = 0; n < NTW; ++n)
                        acc[mt][n] = __builtin_amdgcn_mfma_f32_16x16x32_bf16(af, bf[n], acc[mt][n], 0, 0, 0);
                }
            }
        }
        __syncthreads();  // A_e reused next phase
    }

    // Epilogue. D mapping: col=lane&15, row=(lane>>4)*4+reg [m89].
    const int colo = lane & 15;
    const int row4 = (lane >> 4) * 4;
#pragma unroll
    for (int mt = 0; mt < MT; ++mt) {
#pragma unroll
        for (int n = 0; n < NTW; ++n) {
            int o = nh * COUT + (wn * NTW + n) * 16 + colo;
#pragma unroll
            for (int rr = 0; rr < 4; ++rr) {
                int p = (wm * MT + mt) * 16 + row4 + rr;
                int m = m0 + p;
                if (SPLITOUT) {
                    out[((size_t)kslice * M_TOT + m) * COUTT + o] = acc[mt][n][rr];
                } else {
                    int ow = m % WOUT;
                    int t = m / WOUT;
                    int oh = t % HOUT;
                    int b = t / HOUT;
                    out[((b * COUTT + o) * HOUT + oh) * WOUT + ow] = acc[mt][n][rr];
                }
            }
        }
    }
}

// Deterministic fixed-order reduction of split-K partials -> NCHW (f4 reads).
template <int NS, int COUT, int HOUT, int WOUT>
__global__ __launch_bounds__(256) void reduce_split(const float* __restrict__ P,
                                                    float* __restrict__ out) {
    constexpr int M = 512 * HOUT * WOUT;
    int idx4 = blockIdx.x * 256 + threadIdx.x;
    if (idx4 >= M * COUT / 4) return;
    f32x4 s = {0.f, 0.f, 0.f, 0.f};
#pragma unroll
    for (int i = 0; i < NS; ++i) {
        f32x4 v = *(const f32x4*)&P[(size_t)i * M * COUT + idx4 * 4];
        s += v;
    }
    int o0 = (idx4 * 4) % COUT;   // COUT%4==0 -> 4 consecutive o, same m
    int m = (idx4 * 4) / COUT;
    int ow = m % WOUT;
    int t = m / WOUT;
    int oh = t % HOUT;
    int b = t / HOUT;
#pragma unroll
    for (int q = 0; q < 4; ++q)
        out[((b * COUT + o0 + q) * HOUT + oh) * WOUT + ow] = s[q];
}

// BN stage 1: grid C*S blocks, block (c,s) sums its batch slice -> partials.
template <int C, int HW, int S>
__global__ __launch_bounds__(256) void bn_partial(const float* __restrict__ a,
                                                  float* __restrict__ part) {
    constexpr int BS = 512 / S;
    constexpr int NE = BS * HW;
    int c = blockIdx.x / S, s = blockIdx.x % S;
    int tid = threadIdx.x;
    float sm = 0.f, s2 = 0.f;
    for (int e = tid; e < NE; e += 256) {
        int b = s * BS + e / HW;
        int hw = e % HW;
        float v = a[((size_t)b * C + c) * HW + hw];
        sm += v;
        s2 += v * v;
    }
    __shared__ float r0[256], r1[256];
    r0[tid] = sm; r1[tid] = s2;
    __syncthreads();
    for (int off = 128; off > 0; off >>= 1) {
        if (tid < off) { r0[tid] += r0[tid + off]; r1[tid] += r1[tid + off]; }
        __syncthreads();
    }
    if (tid == 0) {
        part[(c * S + s) * 2] = r0[0];
        part[(c * S + s) * 2 + 1] = r1[0];
    }
}

// BN3-finish + avgpool(2x2) + FC(128->1) + sigmoid. One wave per batch elem.
__global__ void head_ker(const float* __restrict__ a4, const float* __restrict__ part3,
                         const float* __restrict__ g3, const float* __restrict__ b3,
                         const float* __restrict__ fcw, const float* __restrict__ fcb,
                         float* __restrict__ out) {
    int b = blockIdx.x;
    int lane = threadIdx.x;  // 64
    float acc = 0.0f;
#pragma unroll
    for (int j = 0; j < 2; ++j) {
        int o = lane + 64 * j;
        float sm = 0.f, s2 = 0.f;
#pragma unroll
        for (int s = 0; s < 8; ++s) {
            sm += part3[(o * 8 + s) * 2];
            s2 += part3[(o * 8 + s) * 2 + 1];
        }
        float mean = sm * (1.f / 2048.f);
        float var = s2 * (1.f / 2048.f) - mean * mean;
        float rs = rsqrtf(var + 1e-5f);
        float scl = g3[o] * rs;
        float sh = b3[o] - mean * scl;
        const float* p = a4 + (b * 128 + o) * 4;
        float sv = p[0] + p[1] + p[2] + p[3];
        float pooled = fmaf(sv * 0.25f, scl, sh);
        acc = fmaf(pooled, fcw[o], acc);
    }
#pragma unroll
    for (int off = 32; off > 0; off >>= 1) acc += __shfl_down(acc, off);
    if (lane == 0) out[b] = 1.0f / (1.0f + expf(-(acc + fcb[0])));
}

extern "C" void kernel_launch(void* const* d_in, const int* in_sizes, int n_in,
                              void* d_out, int out_size, void* d_ws, size_t ws_size,
                              hipStream_t stream) {
    const float* x   = (const float*)d_in[0];
    const float* bw1 = (const float*)d_in[1];
    const float* sw1 = (const float*)d_in[2];
    const float* sc1 = (const float*)d_in[3];
    const float* bw2 = (const float*)d_in[4];
    const float* sw2 = (const float*)d_in[5];
    const float* sc2 = (const float*)d_in[6];
    const float* bw3 = (const float*)d_in[7];
    const float* sw3 = (const float*)d_in[8];
    const float* sc3 = (const float*)d_in[9];
    const float* bw4 = (const float*)d_in[10];
    const float* sw4 = (const float*)d_in[11];
    const float* sc4 = (const float*)d_in[12];
    const float* g1  = (const float*)d_in[13];
    const float* b1  = (const float*)d_in[14];
    const float* g2  = (const float*)d_in[15];
    const float* b2  = (const float*)d_in[16];
    const float* g3  = (const float*)d_in[17];
    const float* b3  = (const float*)d_in[18];
    const float* fcw = (const float*)d_in[19];
    const float* fcb = (const float*)d_in[20];

    float* ws = (float*)d_ws;
    float* a1 = ws;                    // 4194304 floats (dead after L2 -> P3)
    float* a2 = a1 + 4194304;          // 2097152 (dead after L3 -> P4)
    float* a3 = a2 + 2097152;          // 1048576
    float* a4 = a3 + 1048576;          // 262144
    unsigned short* wf1 = (unsigned short*)(a4 + 262144);  // 12288 ushorts
    unsigned short* wf2 = wf1 + 12288;      // 262144
    unsigned short* wf3 = wf2 + 262144;     // 1048576
    unsigned short* wf4 = wf3 + 1048576;    // 2097152
    float* part1 = (float*)(wf4 + 2097152); // 64*16*2  = 2048
    float* part2 = part1 + 2048;            // 128*16*2 = 4096
    float* part3 = part2 + 4096;            // 128*8*2  = 2048
    float* P3 = a1;                    // 4 * 8192*128 = 4194304 floats
    float* P4 = a2;                    // 8 * 2048*128 = 2097152 floats

    // weight prep: one fragment per thread (427520 frags)
    prep_all<<<1670, 256, 0, stream>>>(bw1, sw1, sc1, bw2, sw2, sc2,
                                       bw3, sw3, sc3, bw4, sw4, sc4,
                                       wf1, wf2, wf3, wf4);

    // L1: (512,3,32,32) -> (512,32,16,16), BM=256 (1 image), single phase UB=3
    kan_conv_fused<3, 32, 1, 16, 16, 4, 1, 4, 3, 3, false, 1, 1, false, 0>
        <<<512, 256, 0, stream>>>(x, wf1, nullptr, nullptr, nullptr, a1);
    // L2: -> (512,64,8,8), BM=128 (2 images), N-split 2, UB=4 (8 phases)
    kan_conv_fused<32, 64, 2, 8, 8, 4, 1, 2, 32, 4, false, 1, 1, false, 0>
        <<<dim3(256, 2), 256, 0, stream>>>(a1, wf2, nullptr, nullptr, nullptr, a2);
    bn_partial<64, 64, 16><<<1024, 256, 0, stream>>>(a2, part1);
    // L3: -> (512,128,4,4), BM=128 (8 images), N-split 2 x K-split 4x16ch,
    // UB=2, BN1 folded in-kernel
    kan_conv_fused<64, 128, 2, 4, 4, 4, 1, 2, 16, 2, true, 16, 32768, true, 1>
        <<<dim3(64, 8), 256, 0, stream>>>(a2, wf3, part1, g1, b1, P3);
    reduce_split<4, 128, 4, 4><<<1024, 256, 0, stream>>>(P3, a3);
    bn_partial<128, 16, 16><<<2048, 256, 0, stream>>>(a3, part2);
    // L4: -> (512,128,2,2), BM=64 (16 images), N-split 2 x K-split 8x16ch,
    // UB=2, BN2 folded in-kernel
    kan_conv_fused<128, 128, 2, 2, 2, 4, 1, 1, 16, 2, true, 16, 8192, true, 0>
        <<<dim3(32, 16), 256, 0, stream>>>(a3, wf4, part2, g2, b2, P4);
    reduce_split<8, 128, 2, 2><<<256, 256, 0, stream>>>(P4, a4);
    bn_partial<128, 4, 8><<<1024, 256, 0, stream>>>(a4, part3);
    // Head: BN3-finish + pool + FC + sigmoid
    head_ker<<<512, 64, 0, stream>>>(a4, part3, g3, b3, fcw, fcb, (float*)d_out);
}

// Round 10
// 203.512 us; speedup vs baseline: 1.0073x; 1.0073x over previous
//
#include <hip/hip_runtime.h>
#include <hip/hip_bf16.h>
#include <math.h>

#define DEVINL __device__ __forceinline__

typedef short short8 __attribute__((ext_vector_type(8)));
typedef float f32x4 __attribute__((ext_vector_type(4)));

DEVINL unsigned short f2bf(float f) {
    union { float f; unsigned int u; } c; c.f = f;
    unsigned int u = c.u;
    return (unsigned short)((u + 0x7fffu + ((u >> 16) & 1u)) >> 16);
}

DEVINL unsigned int packbf2(float a, float b) {
    union { __hip_bfloat162 h; unsigned int u; } c;
    c.h = __float22bfloat162_rn(make_float2(a, b));
    return c.u;  // a low 16, b high 16
}

// Closed-form quadratic B-spline expansion, uniform extended grid
// (knots t_i=(i-2)*(2/3)-1): u=1.5x+3.5, j=floor(u), t=u-j.
// Frag = bf16x8 [relu(x), b0..b4, 0, 0].
DEVINL uint4 expand_frag(float v) {
    float relu = fmaxf(v, 0.f);
    float u = fmaf(v, 1.5f, 3.5f);
    float fj = floorf(u);
    int j = (int)fj;
    float t = u - fj;
    float omt = 1.f - t;
    float v2 = 0.5f * omt * omt;
    float v1 = fmaf(t, omt, 0.5f);
    float v0 = 0.5f * t * t;
    float b[5];
#pragma unroll
    for (int i = 0; i < 5; ++i)
        b[i] = (i == j) ? v0 : (i == j - 1) ? v1 : (i == j - 2) ? v2 : 0.f;
    uint4 r;
    r.x = packbf2(relu, b[0]);
    r.y = packbf2(b[1], b[2]);
    r.z = packbf2(b[3], b[4]);
    r.w = 0u;
    return r;
}

// ---- weight prep: one MFMA B-fragment (8 bf16) per thread ----
// wf[(((c*NTT+nt)*4+ks)*64+lane)*8+j]: tap=ks*4+(lane>>4), o=nt*16+(lane&15),
// j: 0->bw, 1..5->sw*sc, 6,7->0.
DEVINL void prep_frag(int fi, int F, int NTT, const float* __restrict__ bw,
                      const float* __restrict__ sw, const float* __restrict__ sc,
                      unsigned short* __restrict__ wf) {
    int lane = fi & 63;
    int t = fi >> 6;        // (c*NTT+nt)*4 + ks
    int ks = t & 3;
    int t2 = t >> 2;
    int nt = t2 % NTT;
    int c = t2 / NTT;
    int tap = ks * 4 + (lane >> 4);
    int f = c * 16 + tap;
    int o = nt * 16 + (lane & 15);
    float scv = sc[o * F + f];
    float b = bw[o * F + f];
    float s0 = sw[(o * F + f) * 5 + 0] * scv;
    float s1 = sw[(o * F + f) * 5 + 1] * scv;
    float s2 = sw[(o * F + f) * 5 + 2] * scv;
    float s3 = sw[(o * F + f) * 5 + 3] * scv;
    float s4 = sw[(o * F + f) * 5 + 4] * scv;
    uint4 r;
    r.x = packbf2(b, s0);
    r.y = packbf2(s1, s2);
    r.z = packbf2(s3, s4);
    r.w = 0u;
    *(uint4*)&wf[(size_t)fi * 8] = r;
}

__global__ __launch_bounds__(256) void prep_all(
    const float* __restrict__ bw1, const float* __restrict__ sw1, const float* __restrict__ sc1,
    const float* __restrict__ bw2, const float* __restrict__ sw2, const float* __restrict__ sc2,
    const float* __restrict__ bw3, const float* __restrict__ sw3, const float* __restrict__ sc3,
    const float* __restrict__ bw4, const float* __restrict__ sw4, const float* __restrict__ sc4,
    unsigned short* __restrict__ wf1, unsigned short* __restrict__ wf2,
    unsigned short* __restrict__ wf3, unsigned short* __restrict__ wf4) {
    int fi = blockIdx.x * 256 + threadIdx.x;
    const int N1 = 3 * 32 * 16;           // 1536 frags
    const int N2 = 32 * 64 * 16;          // 32768
    const int N3 = 64 * 128 * 16;         // 131072
    const int N4 = 128 * 128 * 16;        // 262144
    if (fi < N1) prep_frag(fi, 48, 2, bw1, sw1, sc1, wf1);
    else if (fi < N1 + N2) prep_frag(fi - N1, 512, 4, bw2, sw2, sc2, wf2);
    else if (fi < N1 + N2 + N3) prep_frag(fi - N1 - N2, 1024, 8, bw3, sw3, sc3, wf3);
    else if (fi < N1 + N2 + N3 + N4) prep_frag(fi - N1 - N2 - N3, 2048, 8, bw4, sw4, sc4, wf4);
}

// ---- pipelined fused KAN conv: issue-early B->regs, A dbuf in LDS ----
// Per group g: {issue B-frag loads for g+1 into alternate reg array; expand
// g+1 into alternate LDS A buffer} overlap {MFMA on group g}; one
// __syncthreads per group. No global->LDS ops in flight (B goes to regs), so
// LDS ds_read(cur) never waits on staging; the sync's vmcnt drain hits loads
// that already completed under the MFMA/expand window. BN scale/shift derived
// in-kernel from partials; NOT applied to padding zeros (pad taps read slot
// 0 = expansion of v=0).
template <int CIN, int COUTT, int NSP, int HOUT, int WOUT, int WM, int WN, int MT,
          int CPS, int UB, bool HASBN, int BNS, int NBN, bool SPLITOUT, int RPAD>
__global__ __launch_bounds__(256) void kan_conv_pipe(
    const float* __restrict__ in, const unsigned short* __restrict__ wf,
    const float* __restrict__ part, const float* __restrict__ gamma,
    const float* __restrict__ beta, float* __restrict__ out) {
    constexpr int HIN = HOUT * 2, WIN = WOUT * 2, W2 = WOUT;
    constexpr int COUT = COUTT / NSP;
    constexpr int NTT = COUTT / 16;
    constexpr int NT = COUT / 16;
    constexpr int NTW = NT / WN;
    constexpr int BM = WM * MT * 16;
    constexpr int IMG_POS = HOUT * WOUT;
    constexpr int NIMG = BM / IMG_POS;
    constexpr int RS = WIN + RPAD;
    constexpr int IMG_STRIDE = HIN * RS + 1;
    constexpr int ASLOTS = NIMG * IMG_STRIDE + 1;  // slot 0 = pad frag
    constexpr int M_TOT = 512 * IMG_POS;
    constexpr int EV = NIMG * HIN * WIN;
    constexpr int EITER = (EV + 255) / 256;
    constexpr int G = CPS / UB;
    constexpr int FR = UB * 4 * NTW;               // B frags held per buffer
    static_assert(WM * WN == 4, "4 waves");
    static_assert(CPS % UB == 0, "UB divides CPS");
    static_assert(EV % 256 == 0, "expand guard-free");

    __shared__ uint4 A_e[2][UB][ASLOTS];

    const int tid = threadIdx.x;
    const int lane = tid & 63;
    const int w = tid >> 6;
    const int wm = w % WM;
    const int wn = w / WM;
    const int g16 = lane >> 4;      // kw
    const int r16 = lane & 15;
    const int m0 = blockIdx.x * BM;
    const int b0 = m0 / IMG_POS;
    const int nh = (NSP > 1) ? ((int)blockIdx.y % NSP) : 0;
    const int kslice = (NSP > 1) ? ((int)blockIdx.y / NSP) : (SPLITOUT ? (int)blockIdx.y : 0);
    const int c0 = SPLITOUT ? kslice * CPS : 0;

    // Per-mt fragment geometry (channel-invariant).
    int aoff[MT];
    int vmask = 0;
#pragma unroll
    for (int mt = 0; mt < MT; ++mt) {
        int p = (wm * MT + mt) * 16 + r16;
        int m = m0 + p;
        int ow = m % WOUT;
        int oh = (m / WOUT) % HOUT;
        int bl = p / IMG_POS;
        int iw = 2 * ow - 1 + g16;
        bool iv = (iw >= 0) && (iw < WIN);
        aoff[mt] = 1 + bl * IMG_STRIDE + (2 * oh) * RS + (iw & 1) * W2 + (iw >> 1);
#pragma unroll
        for (int ks = 0; ks < 4; ++ks) {
            bool vv = iv && !(oh == 0 && ks == 0) && !(oh == HOUT - 1 && ks == 3);
            vmask |= (vv ? 1 : 0) << (mt * 4 + ks);
        }
    }

    if (tid < 2 * UB) A_e[tid / UB][tid % UB][0] = expand_frag(0.f);  // pad slots

    f32x4 acc[MT][NTW];
#pragma unroll
    for (int mt = 0; mt < MT; ++mt)
#pragma unroll
        for (int n = 0; n < NTW; ++n) acc[mt][n] = f32x4{0.f, 0.f, 0.f, 0.f};

    short8 bfA[FR], bfB[FR];

    auto STAGE = [&](int g, short8 (&dst)[FR]) {
#pragma unroll
        for (int u = 0; u < UB; ++u) {
            const int ch = c0 + g * UB + u;
            // per-channel frag block = NTT*2048 ushorts; per-nt block = 2048
            const unsigned short* wfc = wf + (((size_t)ch * NTT + nh * NT) << 11);
#pragma unroll
            for (int ks = 0; ks < 4; ++ks)
#pragma unroll
                for (int n = 0; n < NTW; ++n)
                    dst[(u * 4 + ks) * NTW + n] =
                        *(const short8*)&wfc[((((wn * NTW + n) << 2) + ks) << 9) + (lane << 3)];
        }
    };

    auto EXPAND = [&](int g, int pb) {
#pragma unroll
        for (int u = 0; u < UB; ++u) {
            const int ch = c0 + g * UB + u;
            float bsc = 1.f, bsh = 0.f;
            if (HASBN) {  // uniform scalar reduction of BN partials
                float sm = 0.f, s2 = 0.f;
#pragma unroll 4
                for (int s = 0; s < BNS; ++s) {
                    sm += part[(ch * BNS + s) * 2];
                    s2 += part[(ch * BNS + s) * 2 + 1];
                }
                const float invN = 1.f / (float)NBN;
                float mean = sm * invN;
                float var = s2 * invN - mean * mean;
                float rs = rsqrtf(var + 1e-5f);
                bsc = gamma[ch] * rs;
                bsh = beta[ch] - mean * bsc;
            }
#pragma unroll
            for (int ii = 0; ii < EITER; ++ii) {
                int e = tid + ii * 256;
                int bl = e / (HIN * WIN);
                int r = e - bl * (HIN * WIN);
                int ih = r / WIN;
                int iw = r - ih * WIN;
                float v = in[(((size_t)(b0 + bl) * CIN + ch) * HIN + ih) * WIN + iw];
                if (HASBN) v = fmaf(v, bsc, bsh);
                A_e[pb][u][1 + bl * IMG_STRIDE + ih * RS + (iw & 1) * W2 + (iw >> 1)] = expand_frag(v);
            }
        }
    };

    auto DOMFMA = [&](int pb, const short8 (&bfr)[FR]) {
#pragma unroll
        for (int u = 0; u < UB; ++u) {
#pragma unroll
            for (int ks = 0; ks < 4; ++ks) {
#pragma unroll
                for (int mt = 0; mt < MT; ++mt) {
                    int slot = ((vmask >> (mt * 4 + ks)) & 1) ? (aoff[mt] + (ks - 1) * RS) : 0;
                    short8 af = *(const short8*)&A_e[pb][u][slot];
#pragma unroll
                    for (int n = 0; n < NTW; ++n)
                        acc[mt][n] = __builtin_amdgcn_mfma_f32_16x16x32_bf16(
                            af, bfr[(u * 4 + ks) * NTW + n], acc[mt][n], 0, 0, 0);
                }
            }
        }
    };

    // prologue: group 0 -> buf0/bfA
    STAGE(0, bfA);
    EXPAND(0, 0);
    __syncthreads();
    for (int g = 0; g < G; ++g) {
        if ((g & 1) == 0) {
            if (g + 1 < G) { STAGE(g + 1, bfB); EXPAND(g + 1, 1); }
            DOMFMA(0, bfA);
        } else {
            if (g + 1 < G) { STAGE(g + 1, bfA); EXPAND(g + 1, 0); }
            DOMFMA(1, bfB);
        }
        if (g + 1 < G) __syncthreads();
    }

    // Epilogue. D mapping: col=lane&15, row=(lane>>4)*4+reg [m89].
    const int colo = lane & 15;
    const int row4 = (lane >> 4) * 4;
#pragma unroll
    for (int mt = 0; mt < MT; ++mt) {
#pragma unroll
        for (int n = 0; n < NTW; ++n) {
            int o = nh * COUT + (wn * NTW + n) * 16 + colo;
#pragma unroll
            for (int rr = 0; rr < 4; ++rr) {
                int p = (wm * MT + mt) * 16 + row4 + rr;
                int m = m0 + p;
                if (SPLITOUT) {
                    out[((size_t)kslice * M_TOT + m) * COUTT + o] = acc[mt][n][rr];
                } else {
                    int ow = m % WOUT;
                    int t = m / WOUT;
                    int oh = t % HOUT;
                    int b = t / HOUT;
                    out[((b * COUTT + o) * HOUT + oh) * WOUT + ow] = acc[mt][n][rr];
                }
            }
        }
    }
}

// Deterministic fixed-order reduction of split-K partials -> NCHW (f4 reads).
template <int NS, int COUT, int HOUT, int WOUT>
__global__ __launch_bounds__(256) void reduce_split(const float* __restrict__ P,
                                                    float* __restrict__ out) {
    constexpr int M = 512 * HOUT * WOUT;
    int idx4 = blockIdx.x * 256 + threadIdx.x;
    if (idx4 >= M * COUT / 4) return;
    f32x4 s = {0.f, 0.f, 0.f, 0.f};
#pragma unroll
    for (int i = 0; i < NS; ++i) {
        f32x4 v = *(const f32x4*)&P[(size_t)i * M * COUT + idx4 * 4];
        s += v;
    }
    int o0 = (idx4 * 4) % COUT;   // COUT%4==0 -> 4 consecutive o, same m
    int m = (idx4 * 4) / COUT;
    int ow = m % WOUT;
    int t = m / WOUT;
    int oh = t % HOUT;
    int b = t / HOUT;
#pragma unroll
    for (int q = 0; q < 4; ++q)
        out[((b * COUT + o0 + q) * HOUT + oh) * WOUT + ow] = s[q];
}

// BN stage 1: grid C*S blocks, block (c,s) sums its batch slice -> partials.
template <int C, int HW, int S>
__global__ __launch_bounds__(256) void bn_partial(const float* __restrict__ a,
                                                  float* __restrict__ part) {
    constexpr int BS = 512 / S;
    constexpr int NE = BS * HW;
    int c = blockIdx.x / S, s = blockIdx.x % S;
    int tid = threadIdx.x;
    float sm = 0.f, s2 = 0.f;
    for (int e = tid; e < NE; e += 256) {
        int b = s * BS + e / HW;
        int hw = e % HW;
        float v = a[((size_t)b * C + c) * HW + hw];
        sm += v;
        s2 += v * v;
    }
    __shared__ float r0[256], r1[256];
    r0[tid] = sm; r1[tid] = s2;
    __syncthreads();
    for (int off = 128; off > 0; off >>= 1) {
        if (tid < off) { r0[tid] += r0[tid + off]; r1[tid] += r1[tid + off]; }
        __syncthreads();
    }
    if (tid == 0) {
        part[(c * S + s) * 2] = r0[0];
        part[(c * S + s) * 2 + 1] = r1[0];
    }
}

// BN3-finish + avgpool(2x2) + FC(128->1) + sigmoid. One wave per batch elem.
__global__ void head_ker(const float* __restrict__ a4, const float* __restrict__ part3,
                         const float* __restrict__ g3, const float* __restrict__ b3,
                         const float* __restrict__ fcw, const float* __restrict__ fcb,
                         float* __restrict__ out) {
    int b = blockIdx.x;
    int lane = threadIdx.x;  // 64
    float acc = 0.0f;
#pragma unroll
    for (int j = 0; j < 2; ++j) {
        int o = lane + 64 * j;
        float sm = 0.f, s2 = 0.f;
#pragma unroll
        for (int s = 0; s < 8; ++s) {
            sm += part3[(o * 8 + s) * 2];
            s2 += part3[(o * 8 + s) * 2 + 1];
        }
        float mean = sm * (1.f / 2048.f);
        float var = s2 * (1.f / 2048.f) - mean * mean;
        float rs = rsqrtf(var + 1e-5f);
        float scl = g3[o] * rs;
        float sh = b3[o] - mean * scl;
        const float* p = a4 + (b * 128 + o) * 4;
        float sv = p[0] + p[1] + p[2] + p[3];
        float pooled = fmaf(sv * 0.25f, scl, sh);
        acc = fmaf(pooled, fcw[o], acc);
    }
#pragma unroll
    for (int off = 32; off > 0; off >>= 1) acc += __shfl_down(acc, off);
    if (lane == 0) out[b] = 1.0f / (1.0f + expf(-(acc + fcb[0])));
}

extern "C" void kernel_launch(void* const* d_in, const int* in_sizes, int n_in,
                              void* d_out, int out_size, void* d_ws, size_t ws_size,
                              hipStream_t stream) {
    const float* x   = (const float*)d_in[0];
    const float* bw1 = (const float*)d_in[1];
    const float* sw1 = (const float*)d_in[2];
    const float* sc1 = (const float*)d_in[3];
    const float* bw2 = (const float*)d_in[4];
    const float* sw2 = (const float*)d_in[5];
    const float* sc2 = (const float*)d_in[6];
    const float* bw3 = (const float*)d_in[7];
    const float* sw3 = (const float*)d_in[8];
    const float* sc3 = (const float*)d_in[9];
    const float* bw4 = (const float*)d_in[10];
    const float* sw4 = (const float*)d_in[11];
    const float* sc4 = (const float*)d_in[12];
    const float* g1  = (const float*)d_in[13];
    const float* b1  = (const float*)d_in[14];
    const float* g2  = (const float*)d_in[15];
    const float* b2  = (const float*)d_in[16];
    const float* g3  = (const float*)d_in[17];
    const float* b3  = (const float*)d_in[18];
    const float* fcw = (const float*)d_in[19];
    const float* fcb = (const float*)d_in[20];

    float* ws = (float*)d_ws;
    float* a1 = ws;                    // 4194304 floats (dead after L2 -> P3)
    float* a2 = a1 + 4194304;          // 2097152 (dead after L3 -> P4)
    float* a3 = a2 + 2097152;          // 1048576
    float* a4 = a3 + 1048576;          // 262144
    unsigned short* wf1 = (unsigned short*)(a4 + 262144);  // 12288 ushorts
    unsigned short* wf2 = wf1 + 12288;      // 262144
    unsigned short* wf3 = wf2 + 262144;     // 1048576
    unsigned short* wf4 = wf3 + 1048576;    // 2097152
    float* part1 = (float*)(wf4 + 2097152); // 64*16*2  = 2048
    float* part2 = part1 + 2048;            // 128*16*2 = 4096
    float* part3 = part2 + 4096;            // 128*8*2  = 2048
    float* P3 = a1;                    // 4 * 8192*128 = 4194304 floats
    float* P4 = a2;                    // 8 * 2048*128 = 2097152 floats

    // weight prep: one fragment per thread (427520 frags)
    prep_all<<<1670, 256, 0, stream>>>(bw1, sw1, sc1, bw2, sw2, sc2,
                                       bw3, sw3, sc3, bw4, sw4, sc4,
                                       wf1, wf2, wf3, wf4);

    // L1: (512,3,32,32) -> (512,32,16,16), BM=256, UB=1, G=3 pipelined
    kan_conv_pipe<3, 32, 1, 16, 16, 2, 2, 8, 3, 1, false, 1, 1, false, 0>
        <<<512, 256, 0, stream>>>(x, wf1, nullptr, nullptr, nullptr, a1);
    // L2: -> (512,64,8,8), BM=128, N-split 2, UB=2, G=16 pipelined
    kan_conv_pipe<32, 64, 2, 8, 8, 2, 2, 4, 32, 2, false, 1, 1, false, 0>
        <<<dim3(256, 2), 256, 0, stream>>>(a1, wf2, nullptr, nullptr, nullptr, a2);
    bn_partial<64, 64, 16><<<1024, 256, 0, stream>>>(a2, part1);
    // L3: -> (512,128,4,4), BM=128, N-split 4 x K-split 4x16ch, UB=2, G=8
    kan_conv_pipe<64, 128, 4, 4, 4, 2, 2, 4, 16, 2, true, 16, 32768, true, 1>
        <<<dim3(64, 16), 256, 0, stream>>>(a2, wf3, part1, g1, b1, P3);
    reduce_split<4, 128, 4, 4><<<1024, 256, 0, stream>>>(P3, a3);
    bn_partial<128, 16, 16><<<2048, 256, 0, stream>>>(a3, part2);
    // L4: -> (512,128,2,2), BM=64, N-split 4 x K-split 8x16ch, UB=2, G=8
    kan_conv_pipe<128, 128, 4, 2, 2, 2, 2, 2, 16, 2, true, 16, 8192, true, 0>
        <<<dim3(32, 32), 256, 0, stream>>>(a3, wf4, part2, g2, b2, P4);
    reduce_split<8, 128, 2, 2><<<256, 256, 0, stream>>>(P4, a4);
    bn_partial<128, 4, 8><<<1024, 256, 0, stream>>>(a4, part3);
    // Head: BN3-finish + pool + FC + sigmoid
    head_ker<<<512, 64, 0, stream>>>(a4, part3, g3, b3, fcw, fcb, (float*)d_out);
}

// Round 11
// 170.085 us; speedup vs baseline: 1.2052x; 1.1965x over previous
//
#include <hip/hip_runtime.h>
#include <hip/hip_bf16.h>
#include <math.h>

#define DEVINL __device__ __forceinline__

typedef short short8 __attribute__((ext_vector_type(8)));
typedef float f32x4 __attribute__((ext_vector_type(4)));

DEVINL unsigned short f2bf(float f) {
    union { float f; unsigned int u; } c; c.f = f;
    unsigned int u = c.u;
    return (unsigned short)((u + 0x7fffu + ((u >> 16) & 1u)) >> 16);
}

DEVINL unsigned int packbf2(float a, float b) {
    union { __hip_bfloat162 h; unsigned int u; } c;
    c.h = __float22bfloat162_rn(make_float2(a, b));
    return c.u;  // a low 16, b high 16
}

DEVINL void gload_lds16(const unsigned int* g, unsigned int* l) {
    __builtin_amdgcn_global_load_lds((const __attribute__((address_space(1))) unsigned int*)g,
                                     (__attribute__((address_space(3))) unsigned int*)l, 16, 0, 0);
}

// Closed-form quadratic B-spline expansion, uniform extended grid
// (knots t_i=(i-2)*(2/3)-1): u=1.5x+3.5, j=floor(u), t=u-j.
// Frag = bf16x8 [relu(x), b0..b4, 0, 0].
DEVINL uint4 expand_frag(float v) {
    float relu = fmaxf(v, 0.f);
    float u = fmaf(v, 1.5f, 3.5f);
    float fj = floorf(u);
    int j = (int)fj;
    float t = u - fj;
    float omt = 1.f - t;
    float v2 = 0.5f * omt * omt;
    float v1 = fmaf(t, omt, 0.5f);
    float v0 = 0.5f * t * t;
    float b[5];
#pragma unroll
    for (int i = 0; i < 5; ++i)
        b[i] = (i == j) ? v0 : (i == j - 1) ? v1 : (i == j - 2) ? v2 : 0.f;
    uint4 r;
    r.x = packbf2(relu, b[0]);
    r.y = packbf2(b[1], b[2]);
    r.z = packbf2(b[3], b[4]);
    r.w = 0u;
    return r;
}

// ---- weight prep: one MFMA B-fragment (8 bf16) per thread ----
// wf[(((c*NTT+nt)*4+ks)*64+lane)*8+j]: tap=ks*4+(lane>>4), o=nt*16+(lane&15),
// j: 0->bw, 1..5->sw*sc, 6,7->0.
DEVINL void prep_frag(int fi, int F, int NTT, const float* __restrict__ bw,
                      const float* __restrict__ sw, const float* __restrict__ sc,
                      unsigned short* __restrict__ wf) {
    int lane = fi & 63;
    int t = fi >> 6;        // (c*NTT+nt)*4 + ks
    int ks = t & 3;
    int t2 = t >> 2;
    int nt = t2 % NTT;
    int c = t2 / NTT;
    int tap = ks * 4 + (lane >> 4);
    int f = c * 16 + tap;
    int o = nt * 16 + (lane & 15);
    float scv = sc[o * F + f];
    float b = bw[o * F + f];
    float s0 = sw[(o * F + f) * 5 + 0] * scv;
    float s1 = sw[(o * F + f) * 5 + 1] * scv;
    float s2 = sw[(o * F + f) * 5 + 2] * scv;
    float s3 = sw[(o * F + f) * 5 + 3] * scv;
    float s4 = sw[(o * F + f) * 5 + 4] * scv;
    uint4 r;
    r.x = packbf2(b, s0);
    r.y = packbf2(s1, s2);
    r.z = packbf2(s3, s4);
    r.w = 0u;
    *(uint4*)&wf[(size_t)fi * 8] = r;
}

__global__ __launch_bounds__(256) void prep_all(
    const float* __restrict__ bw1, const float* __restrict__ sw1, const float* __restrict__ sc1,
    const float* __restrict__ bw2, const float* __restrict__ sw2, const float* __restrict__ sc2,
    const float* __restrict__ bw3, const float* __restrict__ sw3, const float* __restrict__ sc3,
    const float* __restrict__ bw4, const float* __restrict__ sw4, const float* __restrict__ sc4,
    unsigned short* __restrict__ wf1, unsigned short* __restrict__ wf2,
    unsigned short* __restrict__ wf3, unsigned short* __restrict__ wf4) {
    int fi = blockIdx.x * 256 + threadIdx.x;
    const int N1 = 3 * 32 * 16;           // 1536 frags
    const int N2 = 32 * 64 * 16;          // 32768
    const int N3 = 64 * 128 * 16;         // 131072
    const int N4 = 128 * 128 * 16;        // 262144
    if (fi < N1) prep_frag(fi, 48, 2, bw1, sw1, sc1, wf1);
    else if (fi < N1 + N2) prep_frag(fi - N1, 512, 4, bw2, sw2, sc2, wf2);
    else if (fi < N1 + N2 + N3) prep_frag(fi - N1 - N2, 1024, 8, bw3, sw3, sc3, wf3);
    else if (fi < N1 + N2 + N3 + N4) prep_frag(fi - N1 - N2 - N3, 2048, 8, bw4, sw4, sc4, wf4);
}

// ---- fused KAN conv (round-7 phased structure: the proven best) ----
// Per phase: stage UB channels' B frags (global_load_lds, this block's N-half)
// + expand UB channels' input tiles into LDS -> one barrier -> UB*4 MFMA
// k-steps -> barrier. NO LDS reads between gload_lds issue and the barrier.
// blockIdx.y = kslice*NSP + nh. BN scale/shift derived in-kernel from
// partials; NOT applied to padding zeros (pad taps read slot 0 = expansion
// of v=0).
template <int CIN, int COUTT, int NSP, int HOUT, int WOUT, int WM, int WN, int MT,
          int CPS, int UB, bool HASBN, int BNS, int NBN, bool SPLITOUT, int RPAD>
__global__ __launch_bounds__(256) void kan_conv_fused(
    const float* __restrict__ in, const unsigned short* __restrict__ wf,
    const float* __restrict__ part, const float* __restrict__ gamma,
    const float* __restrict__ beta, float* __restrict__ out) {
    constexpr int HIN = HOUT * 2, WIN = WOUT * 2, W2 = WOUT;
    constexpr int COUT = COUTT / NSP;       // this block's N extent
    constexpr int NTT = COUTT / 16;
    constexpr int NT = COUT / 16;
    constexpr int NTW = NT / WN;
    constexpr int BM = WM * MT * 16;
    constexpr int IMG_POS = HOUT * WOUT;
    constexpr int NIMG = BM / IMG_POS;
    constexpr int RS = WIN + RPAD;
    constexpr int IMG_STRIDE = HIN * RS + 1;
    constexpr int ASLOTS = NIMG * IMG_STRIDE + 1;  // slot 0 = pad frag
    constexpr int M_TOT = 512 * IMG_POS;
    constexpr int EV = NIMG * HIN * WIN;
    constexpr int EITER = (EV + 255) / 256;
    static_assert(WM * WN == 4, "4 waves");
    static_assert(CPS % UB == 0, "UB divides CPS");

    __shared__ uint4 A_e[UB][ASLOTS];
    __shared__ uint4 B_l[UB][COUT * 16];

    const int tid = threadIdx.x;
    const int lane = tid & 63;
    const int w = tid >> 6;
    const int wm = w % WM;
    const int wn = w / WM;
    const int g = lane >> 4;        // kw
    const int r16 = lane & 15;
    const int m0 = blockIdx.x * BM;
    const int b0 = m0 / IMG_POS;
    const int nh = (NSP > 1) ? ((int)blockIdx.y % NSP) : 0;
    const int kslice = (NSP > 1) ? ((int)blockIdx.y / NSP) : (SPLITOUT ? (int)blockIdx.y : 0);
    const int c0 = SPLITOUT ? kslice * CPS : 0;

    // Per-mt fragment geometry (channel-invariant).
    int aoff[MT];
    int vmask = 0;
#pragma unroll
    for (int mt = 0; mt < MT; ++mt) {
        int p = (wm * MT + mt) * 16 + r16;
        int m = m0 + p;
        int ow = m % WOUT;
        int oh = (m / WOUT) % HOUT;
        int bl = p / IMG_POS;
        int iw = 2 * ow - 1 + g;
        bool iv = (iw >= 0) && (iw < WIN);
        aoff[mt] = 1 + bl * IMG_STRIDE + (2 * oh) * RS + (iw & 1) * W2 + (iw >> 1);
#pragma unroll
        for (int ks = 0; ks < 4; ++ks) {
            bool vv = iv && !(oh == 0 && ks == 0) && !(oh == HOUT - 1 && ks == 3);
            vmask |= (vv ? 1 : 0) << (mt * 4 + ks);
        }
    }

    if (tid < UB) A_e[tid][0] = expand_frag(0.f);  // pad slots, covered by 1st barrier

    f32x4 acc[MT][NTW];
#pragma unroll
    for (int mt = 0; mt < MT; ++mt)
#pragma unroll
        for (int n = 0; n < NTW; ++n) acc[mt][n] = f32x4{0.f, 0.f, 0.f, 0.f};

    for (int cc = 0; cc < CPS; cc += UB) {
        // (1) issue all B staging for the UB channels (in flight during (2))
#pragma unroll
        for (int u = 0; u < UB; ++u) {
            const int ch = c0 + cc + u;
            const unsigned int* bsrc = (const unsigned int*)wf + ((size_t)ch * NTT + nh * NT) * 1024;
            unsigned int* bdst = (unsigned int*)&B_l[u][0];
#pragma unroll
            for (int r2 = 0; r2 < NT; ++r2)
                gload_lds16(bsrc + (r2 << 10) + tid * 4, bdst + (r2 << 10) + tid * 4);
        }
        // (2) expand UB channels' tiles (once per element); BN-finish folded
#pragma unroll
        for (int u = 0; u < UB; ++u) {
            const int ch = c0 + cc + u;
            float bsc = 1.f, bsh = 0.f;
            if (HASBN) {  // uniform scalar reduction of BN partials
                float sm = 0.f, s2 = 0.f;
#pragma unroll 4
                for (int s = 0; s < BNS; ++s) {
                    sm += part[(ch * BNS + s) * 2];
                    s2 += part[(ch * BNS + s) * 2 + 1];
                }
                const float invN = 1.f / (float)NBN;
                float mean = sm * invN;
                float var = s2 * invN - mean * mean;
                float rs = rsqrtf(var + 1e-5f);
                bsc = gamma[ch] * rs;
                bsh = beta[ch] - mean * bsc;
            }
#pragma unroll
            for (int ii = 0; ii < EITER; ++ii) {
                int e = tid + ii * 256;
                if ((EV % 256 == 0) || e < EV) {
                    int bl = e / (HIN * WIN);
                    int r = e - bl * (HIN * WIN);
                    int ih = r / WIN;
                    int iw = r - ih * WIN;
                    float v = in[(((size_t)(b0 + bl) * CIN + ch) * HIN + ih) * WIN + iw];
                    if (HASBN) v = fmaf(v, bsc, bsh);
                    A_e[u][1 + bl * IMG_STRIDE + ih * RS + (iw & 1) * W2 + (iw >> 1)] = expand_frag(v);
                }
            }
        }
        __syncthreads();  // drains gload_lds (vmcnt) + ds_writes (lgkm)
        // (3) MFMA: UB x 4 k-steps x MT x NTW
#pragma unroll
        for (int u = 0; u < UB; ++u) {
#pragma unroll
            for (int ks = 0; ks < 4; ++ks) {
                short8 bf[NTW];
#pragma unroll
                for (int n = 0; n < NTW; ++n)
                    bf[n] = *(const short8*)&B_l[u][(((wn * NTW + n) * 4 + ks) << 6) + lane];
#pragma unroll
                for (int mt = 0; mt < MT; ++mt) {
                    int slot = ((vmask >> (mt * 4 + ks)) & 1) ? (aoff[mt] + (ks - 1) * RS) : 0;
                    short8 af = *(const short8*)&A_e[u][slot];
#pragma unroll
                    for (int n = 0; n < NTW; ++n)
                        acc[mt][n] = __builtin_amdgcn_mfma_f32_16x16x32_bf16(af, bf[n], acc[mt][n], 0, 0, 0);
                }
            }
        }
        __syncthreads();  // buffers reused next phase
    }

    // Epilogue. D mapping: col=lane&15, row=(lane>>4)*4+reg [m89].
    const int colo = lane & 15;
    const int row4 = (lane >> 4) * 4;
#pragma unroll
    for (int mt = 0; mt < MT; ++mt) {
#pragma unroll
        for (int n = 0; n < NTW; ++n) {
            int o = nh * COUT + (wn * NTW + n) * 16 + colo;
#pragma unroll
            for (int rr = 0; rr < 4; ++rr) {
                int p = (wm * MT + mt) * 16 + row4 + rr;
                int m = m0 + p;
                if (SPLITOUT) {
                    out[((size_t)kslice * M_TOT + m) * COUTT + o] = acc[mt][n][rr];
                } else {
                    int ow = m % WOUT;
                    int t = m / WOUT;
                    int oh = t % HOUT;
                    int b = t / HOUT;
                    out[((b * COUTT + o) * HOUT + oh) * WOUT + ow] = acc[mt][n][rr];
                }
            }
        }
    }
}

// ---- fused split-K reduce + BN partial stats ----
// Grid-stride over idx4; per-thread channel set is CONSTANT because
// (256*4)%COUT==0 and (NB*256*4)%COUT==0. Writes NCHW output and per-block
// channel partials (deterministic LDS tree).
template <int NS, int COUT, int HOUT, int WOUT, int NB>
__global__ __launch_bounds__(256) void reduce_bn(const float* __restrict__ P,
                                                 float* __restrict__ out,
                                                 float* __restrict__ part) {
    constexpr int M = 512 * HOUT * WOUT;
    constexpr int TOT4 = M * COUT / 4;
    static_assert(COUT == 128, "LDS reduce assumes 128 channels");
    const int tid = threadIdx.x;
    float sm[4] = {0.f, 0.f, 0.f, 0.f}, sq[4] = {0.f, 0.f, 0.f, 0.f};
    for (int idx4 = blockIdx.x * 256 + tid; idx4 < TOT4; idx4 += NB * 256) {
        f32x4 s = {0.f, 0.f, 0.f, 0.f};
#pragma unroll
        for (int i = 0; i < NS; ++i)
            s += *(const f32x4*)&P[(size_t)i * M * COUT + (size_t)idx4 * 4];
        int o0 = (idx4 * 4) % COUT;
        int m = (idx4 * 4) / COUT;
        int ow = m % WOUT;
        int t = m / WOUT;
        int oh = t % HOUT;
        int b = t / HOUT;
#pragma unroll
        for (int q = 0; q < 4; ++q) {
            out[((b * COUT + o0 + q) * HOUT + oh) * WOUT + ow] = s[q];
            sm[q] += s[q];
            sq[q] += s[q] * s[q];
        }
    }
    __shared__ float red[2][COUT][8];
    int gch = tid & 31, h = tid >> 5;   // channel group, 8 threads each
#pragma unroll
    for (int q = 0; q < 4; ++q) {
        red[0][gch * 4 + q][h] = sm[q];
        red[1][gch * 4 + q][h] = sq[q];
    }
    __syncthreads();
    int st = tid >> 7;   // 0=sum, 1=sumsq
    int c = tid & 127;
    float v = 0.f;
#pragma unroll
    for (int k = 0; k < 8; ++k) v += red[st][c][k];
    part[((size_t)c * NB + blockIdx.x) * 2 + st] = v;
}

// BN stage 1 (for L2 output a2, NCHW): block (c,s), float4 reads.
template <int C, int HW, int S>
__global__ __launch_bounds__(256) void bn_partial(const float* __restrict__ a,
                                                  float* __restrict__ part) {
    constexpr int BS = 512 / S;
    constexpr int H4 = HW / 4;
    int c = blockIdx.x / S, s = blockIdx.x % S;
    int tid = threadIdx.x;
    float sm = 0.f, s2 = 0.f;
    for (int i = tid; i < BS * H4; i += 256) {
        int b = i / H4, r = i - (i / H4) * H4;
        f32x4 v = *(const f32x4*)&a[(((size_t)(s * BS + b) * C + c) * HW) + r * 4];
#pragma unroll
        for (int q = 0; q < 4; ++q) { sm += v[q]; s2 += v[q] * v[q]; }
    }
    __shared__ float r0[256], r1[256];
    r0[tid] = sm; r1[tid] = s2;
    __syncthreads();
    for (int off = 128; off > 0; off >>= 1) {
        if (tid < off) { r0[tid] += r0[tid + off]; r1[tid] += r1[tid + off]; }
        __syncthreads();
    }
    if (tid == 0) {
        part[(c * S + s) * 2] = r0[0];
        part[(c * S + s) * 2 + 1] = r1[0];
    }
}

// BN3-finish + avgpool(2x2) + FC(128->1) + sigmoid. One wave per batch elem.
template <int S3>
__global__ void head_ker(const float* __restrict__ a4, const float* __restrict__ part3,
                         const float* __restrict__ g3, const float* __restrict__ b3,
                         const float* __restrict__ fcw, const float* __restrict__ fcb,
                         float* __restrict__ out) {
    int b = blockIdx.x;
    int lane = threadIdx.x;  // 64
    float acc = 0.0f;
#pragma unroll
    for (int j = 0; j < 2; ++j) {
        int o = lane + 64 * j;
        float sm = 0.f, s2 = 0.f;
#pragma unroll 4
        for (int s = 0; s < S3; ++s) {
            sm += part3[(o * S3 + s) * 2];
            s2 += part3[(o * S3 + s) * 2 + 1];
        }
        float mean = sm * (1.f / 2048.f);
        float var = s2 * (1.f / 2048.f) - mean * mean;
        float rs = rsqrtf(var + 1e-5f);
        float scl = g3[o] * rs;
        float sh = b3[o] - mean * scl;
        const float* p = a4 + (b * 128 + o) * 4;
        float sv = p[0] + p[1] + p[2] + p[3];
        float pooled = fmaf(sv * 0.25f, scl, sh);
        acc = fmaf(pooled, fcw[o], acc);
    }
#pragma unroll
    for (int off = 32; off > 0; off >>= 1) acc += __shfl_down(acc, off);
    if (lane == 0) out[b] = 1.0f / (1.0f + expf(-(acc + fcb[0])));
}

extern "C" void kernel_launch(void* const* d_in, const int* in_sizes, int n_in,
                              void* d_out, int out_size, void* d_ws, size_t ws_size,
                              hipStream_t stream) {
    const float* x   = (const float*)d_in[0];
    const float* bw1 = (const float*)d_in[1];
    const float* sw1 = (const float*)d_in[2];
    const float* sc1 = (const float*)d_in[3];
    const float* bw2 = (const float*)d_in[4];
    const float* sw2 = (const float*)d_in[5];
    const float* sc2 = (const float*)d_in[6];
    const float* bw3 = (const float*)d_in[7];
    const float* sw3 = (const float*)d_in[8];
    const float* sc3 = (const float*)d_in[9];
    const float* bw4 = (const float*)d_in[10];
    const float* sw4 = (const float*)d_in[11];
    const float* sc4 = (const float*)d_in[12];
    const float* g1  = (const float*)d_in[13];
    const float* b1  = (const float*)d_in[14];
    const float* g2  = (const float*)d_in[15];
    const float* b2  = (const float*)d_in[16];
    const float* g3  = (const float*)d_in[17];
    const float* b3  = (const float*)d_in[18];
    const float* fcw = (const float*)d_in[19];
    const float* fcb = (const float*)d_in[20];

    float* ws = (float*)d_ws;
    float* a1 = ws;                    // 4194304 floats (dead after L2 -> P3)
    float* a2 = a1 + 4194304;          // 2097152 (dead after L3 -> P4)
    float* a3 = a2 + 2097152;          // 1048576
    float* a4 = a3 + 1048576;          // 262144
    unsigned short* wf1 = (unsigned short*)(a4 + 262144);  // 12288 ushorts
    unsigned short* wf2 = wf1 + 12288;      // 262144
    unsigned short* wf3 = wf2 + 262144;     // 1048576
    unsigned short* wf4 = wf3 + 1048576;    // 2097152
    float* part1 = (float*)(wf4 + 2097152); // 64*16*2  = 2048
    float* part2 = part1 + 2048;            // 128*32*2 = 8192
    float* part3 = part2 + 8192;            // 128*32*2 = 8192
    float* P3 = a1;                    // 4 * 8192*128 = 4194304 floats
    float* P4 = a2;                    // 8 * 2048*128 = 2097152 floats

    // weight prep: one fragment per thread (427520 frags)
    prep_all<<<1670, 256, 0, stream>>>(bw1, sw1, sc1, bw2, sw2, sc2,
                                       bw3, sw3, sc3, bw4, sw4, sc4,
                                       wf1, wf2, wf3, wf4);

    // L1: (512,3,32,32) -> (512,32,16,16), BM=256 (1 image), single phase UB=3
    kan_conv_fused<3, 32, 1, 16, 16, 4, 1, 4, 3, 3, false, 1, 1, false, 0>
        <<<512, 256, 0, stream>>>(x, wf1, nullptr, nullptr, nullptr, a1);
    // L2: -> (512,64,8,8), BM=128 (2 images), N-split 2, UB=2 (16 phases),
    // LDS 32.5KB -> 4 blocks/CU
    kan_conv_fused<32, 64, 2, 8, 8, 4, 1, 2, 32, 2, false, 1, 1, false, 0>
        <<<dim3(256, 2), 256, 0, stream>>>(a1, wf2, nullptr, nullptr, nullptr, a2);
    bn_partial<64, 64, 16><<<1024, 256, 0, stream>>>(a2, part1);
    // L3: -> (512,128,4,4), BM=128 (8 images), N-split 2 x K-split 4x16ch,
    // UB=2, BN1 folded in-kernel
    kan_conv_fused<64, 128, 2, 4, 4, 4, 1, 2, 16, 2, true, 16, 32768, true, 1>
        <<<dim3(64, 8), 256, 0, stream>>>(a2, wf3, part1, g1, b1, P3);
    // fused reduce(P3 -> a3) + BN2 partials
    reduce_bn<4, 128, 4, 4, 32><<<32, 256, 0, stream>>>(P3, a3, part2);
    // L4: -> (512,128,2,2), BM=64 (16 images), N-split 2 x K-split 8x16ch,
    // UB=2, BN2 folded in-kernel (BNS=32 from reduce_bn)
    kan_conv_fused<128, 128, 2, 2, 2, 4, 1, 1, 16, 2, true, 32, 8192, true, 0>
        <<<dim3(32, 16), 256, 0, stream>>>(a3, wf4, part2, g2, b2, P4);
    // fused reduce(P4 -> a4) + BN3 partials
    reduce_bn<8, 128, 2, 2, 32><<<32, 256, 0, stream>>>(P4, a4, part3);
    // Head: BN3-finish + pool + FC + sigmoid
    head_ker<32><<<512, 64, 0, stream>>>(a4, part3, g3, b3, fcw, fcb, (float*)d_out);
}

// Round 12
// 137.618 us; speedup vs baseline: 1.4896x; 1.2359x over previous
//
#include <hip/hip_runtime.h>
#include <hip/hip_bf16.h>
#include <math.h>

#define DEVINL __device__ __forceinline__

typedef short short8 __attribute__((ext_vector_type(8)));
typedef float f32x4 __attribute__((ext_vector_type(4)));

DEVINL unsigned short f2bf(float f) {
    union { float f; unsigned int u; } c; c.f = f;
    unsigned int u = c.u;
    return (unsigned short)((u + 0x7fffu + ((u >> 16) & 1u)) >> 16);
}

DEVINL unsigned int packbf2(float a, float b) {
    union { __hip_bfloat162 h; unsigned int u; } c;
    c.h = __float22bfloat162_rn(make_float2(a, b));
    return c.u;  // a low 16, b high 16
}

DEVINL void gload_lds16(const unsigned int* g, unsigned int* l) {
    __builtin_amdgcn_global_load_lds((const __attribute__((address_space(1))) unsigned int*)g,
                                     (__attribute__((address_space(3))) unsigned int*)l, 16, 0, 0);
}

// Closed-form quadratic B-spline expansion, uniform extended grid
// (knots t_i=(i-2)*(2/3)-1): u=1.5x+3.5, j=floor(u), t=u-j.
// Frag = bf16x8 [relu(x), b0..b4, 0, 0].
DEVINL uint4 expand_frag(float v) {
    float relu = fmaxf(v, 0.f);
    float u = fmaf(v, 1.5f, 3.5f);
    float fj = floorf(u);
    int j = (int)fj;
    float t = u - fj;
    float omt = 1.f - t;
    float v2 = 0.5f * omt * omt;
    float v1 = fmaf(t, omt, 0.5f);
    float v0 = 0.5f * t * t;
    float b[5];
#pragma unroll
    for (int i = 0; i < 5; ++i)
        b[i] = (i == j) ? v0 : (i == j - 1) ? v1 : (i == j - 2) ? v2 : 0.f;
    uint4 r;
    r.x = packbf2(relu, b[0]);
    r.y = packbf2(b[1], b[2]);
    r.z = packbf2(b[3], b[4]);
    r.w = 0u;
    return r;
}

// ---- weight prep: one MFMA B-fragment (8 bf16) per thread ----
// wf[(((c*NTT+nt)*4+ks)*64+lane)*8+j]: tap=ks*4+(lane>>4), o=nt*16+(lane&15),
// j: 0->bw, 1..5->sw*sc, 6,7->0.
DEVINL void prep_frag(int fi, int F, int NTT, const float* __restrict__ bw,
                      const float* __restrict__ sw, const float* __restrict__ sc,
                      unsigned short* __restrict__ wf) {
    int lane = fi & 63;
    int t = fi >> 6;        // (c*NTT+nt)*4 + ks
    int ks = t & 3;
    int t2 = t >> 2;
    int nt = t2 % NTT;
    int c = t2 / NTT;
    int tap = ks * 4 + (lane >> 4);
    int f = c * 16 + tap;
    int o = nt * 16 + (lane & 15);
    float scv = sc[o * F + f];
    float b = bw[o * F + f];
    float s0 = sw[(o * F + f) * 5 + 0] * scv;
    float s1 = sw[(o * F + f) * 5 + 1] * scv;
    float s2 = sw[(o * F + f) * 5 + 2] * scv;
    float s3 = sw[(o * F + f) * 5 + 3] * scv;
    float s4 = sw[(o * F + f) * 5 + 4] * scv;
    uint4 r;
    r.x = packbf2(b, s0);
    r.y = packbf2(s1, s2);
    r.z = packbf2(s3, s4);
    r.w = 0u;
    *(uint4*)&wf[(size_t)fi * 8] = r;
}

__global__ __launch_bounds__(256) void prep_all(
    const float* __restrict__ bw1, const float* __restrict__ sw1, const float* __restrict__ sc1,
    const float* __restrict__ bw2, const float* __restrict__ sw2, const float* __restrict__ sc2,
    const float* __restrict__ bw3, const float* __restrict__ sw3, const float* __restrict__ sc3,
    const float* __restrict__ bw4, const float* __restrict__ sw4, const float* __restrict__ sc4,
    unsigned short* __restrict__ wf1, unsigned short* __restrict__ wf2,
    unsigned short* __restrict__ wf3, unsigned short* __restrict__ wf4) {
    int fi = blockIdx.x * 256 + threadIdx.x;
    const int N1 = 3 * 32 * 16;           // 1536 frags
    const int N2 = 32 * 64 * 16;          // 32768
    const int N3 = 64 * 128 * 16;         // 131072
    const int N4 = 128 * 128 * 16;        // 262144
    if (fi < N1) prep_frag(fi, 48, 2, bw1, sw1, sc1, wf1);
    else if (fi < N1 + N2) prep_frag(fi - N1, 512, 4, bw2, sw2, sc2, wf2);
    else if (fi < N1 + N2 + N3) prep_frag(fi - N1 - N2, 1024, 8, bw3, sw3, sc3, wf3);
    else if (fi < N1 + N2 + N3 + N4) prep_frag(fi - N1 - N2 - N3, 2048, 8, bw4, sw4, sc4, wf4);
}

// ---- fused KAN conv (round-7 phased structure: the proven best) ----
// Per phase: stage UB channels' B frags (global_load_lds, this block's N-half)
// + expand UB channels' input tiles into LDS -> one barrier -> UB*4 MFMA
// k-steps -> barrier. NO LDS reads between gload_lds issue and the barrier.
// blockIdx.y = kslice*NSP + nh. BN scale/shift derived in-kernel from
// partials; NOT applied to padding zeros (pad taps read slot 0 = expansion
// of v=0).
template <int CIN, int COUTT, int NSP, int HOUT, int WOUT, int WM, int WN, int MT,
          int CPS, int UB, bool HASBN, int BNS, int NBN, bool SPLITOUT, int RPAD>
__global__ __launch_bounds__(256) void kan_conv_fused(
    const float* __restrict__ in, const unsigned short* __restrict__ wf,
    const float* __restrict__ part, const float* __restrict__ gamma,
    const float* __restrict__ beta, float* __restrict__ out) {
    constexpr int HIN = HOUT * 2, WIN = WOUT * 2, W2 = WOUT;
    constexpr int COUT = COUTT / NSP;       // this block's N extent
    constexpr int NTT = COUTT / 16;
    constexpr int NT = COUT / 16;
    constexpr int NTW = NT / WN;
    constexpr int BM = WM * MT * 16;
    constexpr int IMG_POS = HOUT * WOUT;
    constexpr int NIMG = BM / IMG_POS;
    constexpr int RS = WIN + RPAD;
    constexpr int IMG_STRIDE = HIN * RS + 1;
    constexpr int ASLOTS = NIMG * IMG_STRIDE + 1;  // slot 0 = pad frag
    constexpr int M_TOT = 512 * IMG_POS;
    constexpr int EV = NIMG * HIN * WIN;
    constexpr int EITER = (EV + 255) / 256;
    static_assert(WM * WN == 4, "4 waves");
    static_assert(CPS % UB == 0, "UB divides CPS");

    __shared__ uint4 A_e[UB][ASLOTS];
    __shared__ uint4 B_l[UB][COUT * 16];

    const int tid = threadIdx.x;
    const int lane = tid & 63;
    const int w = tid >> 6;
    const int wm = w % WM;
    const int wn = w / WM;
    const int g = lane >> 4;        // kw
    const int r16 = lane & 15;
    const int m0 = blockIdx.x * BM;
    const int b0 = m0 / IMG_POS;
    const int nh = (NSP > 1) ? ((int)blockIdx.y % NSP) : 0;
    const int kslice = (NSP > 1) ? ((int)blockIdx.y / NSP) : (SPLITOUT ? (int)blockIdx.y : 0);
    const int c0 = SPLITOUT ? kslice * CPS : 0;

    // Per-mt fragment geometry (channel-invariant).
    int aoff[MT];
    int vmask = 0;
#pragma unroll
    for (int mt = 0; mt < MT; ++mt) {
        int p = (wm * MT + mt) * 16 + r16;
        int m = m0 + p;
        int ow = m % WOUT;
        int oh = (m / WOUT) % HOUT;
        int bl = p / IMG_POS;
        int iw = 2 * ow - 1 + g;
        bool iv = (iw >= 0) && (iw < WIN);
        aoff[mt] = 1 + bl * IMG_STRIDE + (2 * oh) * RS + (iw & 1) * W2 + (iw >> 1);
#pragma unroll
        for (int ks = 0; ks < 4; ++ks) {
            bool vv = iv && !(oh == 0 && ks == 0) && !(oh == HOUT - 1 && ks == 3);
            vmask |= (vv ? 1 : 0) << (mt * 4 + ks);
        }
    }

    if (tid < UB) A_e[tid][0] = expand_frag(0.f);  // pad slots, covered by 1st barrier

    f32x4 acc[MT][NTW];
#pragma unroll
    for (int mt = 0; mt < MT; ++mt)
#pragma unroll
        for (int n = 0; n < NTW; ++n) acc[mt][n] = f32x4{0.f, 0.f, 0.f, 0.f};

    for (int cc = 0; cc < CPS; cc += UB) {
        // (1) issue all B staging for the UB channels (in flight during (2))
#pragma unroll
        for (int u = 0; u < UB; ++u) {
            const int ch = c0 + cc + u;
            const unsigned int* bsrc = (const unsigned int*)wf + ((size_t)ch * NTT + nh * NT) * 1024;
            unsigned int* bdst = (unsigned int*)&B_l[u][0];
#pragma unroll
            for (int r2 = 0; r2 < NT; ++r2)
                gload_lds16(bsrc + (r2 << 10) + tid * 4, bdst + (r2 << 10) + tid * 4);
        }
        // (2) expand UB channels' tiles (once per element); BN-finish folded
#pragma unroll
        for (int u = 0; u < UB; ++u) {
            const int ch = c0 + cc + u;
            float bsc = 1.f, bsh = 0.f;
            if (HASBN) {  // uniform scalar reduction of BN partials
                float sm = 0.f, s2 = 0.f;
#pragma unroll 4
                for (int s = 0; s < BNS; ++s) {
                    sm += part[(ch * BNS + s) * 2];
                    s2 += part[(ch * BNS + s) * 2 + 1];
                }
                const float invN = 1.f / (float)NBN;
                float mean = sm * invN;
                float var = s2 * invN - mean * mean;
                float rs = rsqrtf(var + 1e-5f);
                bsc = gamma[ch] * rs;
                bsh = beta[ch] - mean * bsc;
            }
#pragma unroll
            for (int ii = 0; ii < EITER; ++ii) {
                int e = tid + ii * 256;
                if ((EV % 256 == 0) || e < EV) {
                    int bl = e / (HIN * WIN);
                    int r = e - bl * (HIN * WIN);
                    int ih = r / WIN;
                    int iw = r - ih * WIN;
                    float v = in[(((size_t)(b0 + bl) * CIN + ch) * HIN + ih) * WIN + iw];
                    if (HASBN) v = fmaf(v, bsc, bsh);
                    A_e[u][1 + bl * IMG_STRIDE + ih * RS + (iw & 1) * W2 + (iw >> 1)] = expand_frag(v);
                }
            }
        }
        __syncthreads();  // drains gload_lds (vmcnt) + ds_writes (lgkm)
        // (3) MFMA: UB x 4 k-steps x MT x NTW
#pragma unroll
        for (int u = 0; u < UB; ++u) {
#pragma unroll
            for (int ks = 0; ks < 4; ++ks) {
                short8 bf[NTW];
#pragma unroll
                for (int n = 0; n < NTW; ++n)
                    bf[n] = *(const short8*)&B_l[u][(((wn * NTW + n) * 4 + ks) << 6) + lane];
#pragma unroll
                for (int mt = 0; mt < MT; ++mt) {
                    int slot = ((vmask >> (mt * 4 + ks)) & 1) ? (aoff[mt] + (ks - 1) * RS) : 0;
                    short8 af = *(const short8*)&A_e[u][slot];
#pragma unroll
                    for (int n = 0; n < NTW; ++n)
                        acc[mt][n] = __builtin_amdgcn_mfma_f32_16x16x32_bf16(af, bf[n], acc[mt][n], 0, 0, 0);
                }
            }
        }
        __syncthreads();  // buffers reused next phase
    }

    // Epilogue. D mapping: col=lane&15, row=(lane>>4)*4+reg [m89].
    const int colo = lane & 15;
    const int row4 = (lane >> 4) * 4;
#pragma unroll
    for (int mt = 0; mt < MT; ++mt) {
#pragma unroll
        for (int n = 0; n < NTW; ++n) {
            int o = nh * COUT + (wn * NTW + n) * 16 + colo;
#pragma unroll
            for (int rr = 0; rr < 4; ++rr) {
                int p = (wm * MT + mt) * 16 + row4 + rr;
                int m = m0 + p;
                if (SPLITOUT) {
                    out[((size_t)kslice * M_TOT + m) * COUTT + o] = acc[mt][n][rr];
                } else {
                    int ow = m % WOUT;
                    int t = m / WOUT;
                    int oh = t % HOUT;
                    int b = t / HOUT;
                    out[((b * COUTT + o) * HOUT + oh) * WOUT + ow] = acc[mt][n][rr];
                }
            }
        }
    }
}

// Deterministic fixed-order reduction of split-K partials -> NCHW (f4 reads).
template <int NS, int COUT, int HOUT, int WOUT>
__global__ __launch_bounds__(256) void reduce_split(const float* __restrict__ P,
                                                    float* __restrict__ out) {
    constexpr int M = 512 * HOUT * WOUT;
    int idx4 = blockIdx.x * 256 + threadIdx.x;
    if (idx4 >= M * COUT / 4) return;
    f32x4 s = {0.f, 0.f, 0.f, 0.f};
#pragma unroll
    for (int i = 0; i < NS; ++i) {
        f32x4 v = *(const f32x4*)&P[(size_t)i * M * COUT + idx4 * 4];
        s += v;
    }
    int o0 = (idx4 * 4) % COUT;   // COUT%4==0 -> 4 consecutive o, same m
    int m = (idx4 * 4) / COUT;
    int ow = m % WOUT;
    int t = m / WOUT;
    int oh = t % HOUT;
    int b = t / HOUT;
#pragma unroll
    for (int q = 0; q < 4; ++q)
        out[((b * COUT + o0 + q) * HOUT + oh) * WOUT + ow] = s[q];
}

// BN stage 1: grid C*S blocks, block (c,s) sums its batch slice; float4 reads.
template <int C, int HW, int S>
__global__ __launch_bounds__(256) void bn_partial(const float* __restrict__ a,
                                                  float* __restrict__ part) {
    constexpr int BS = 512 / S;
    constexpr int H4 = HW / 4;
    int c = blockIdx.x / S, s = blockIdx.x % S;
    int tid = threadIdx.x;
    float sm = 0.f, s2 = 0.f;
    for (int i = tid; i < BS * H4; i += 256) {
        int b = i / H4, r = i - (i / H4) * H4;
        f32x4 v = *(const f32x4*)&a[(((size_t)(s * BS + b) * C + c) * HW) + r * 4];
#pragma unroll
        for (int q = 0; q < 4; ++q) { sm += v[q]; s2 += v[q] * v[q]; }
    }
    __shared__ float r0[256], r1[256];
    r0[tid] = sm; r1[tid] = s2;
    __syncthreads();
    for (int off = 128; off > 0; off >>= 1) {
        if (tid < off) { r0[tid] += r0[tid + off]; r1[tid] += r1[tid + off]; }
        __syncthreads();
    }
    if (tid == 0) {
        part[(c * S + s) * 2] = r0[0];
        part[(c * S + s) * 2 + 1] = r1[0];
    }
}

// BN3-finish + avgpool(2x2) + FC(128->1) + sigmoid. One wave per batch elem.
template <int S3>
__global__ void head_ker(const float* __restrict__ a4, const float* __restrict__ part3,
                         const float* __restrict__ g3, const float* __restrict__ b3,
                         const float* __restrict__ fcw, const float* __restrict__ fcb,
                         float* __restrict__ out) {
    int b = blockIdx.x;
    int lane = threadIdx.x;  // 64
    float acc = 0.0f;
#pragma unroll
    for (int j = 0; j < 2; ++j) {
        int o = lane + 64 * j;
        float sm = 0.f, s2 = 0.f;
#pragma unroll
        for (int s = 0; s < S3; ++s) {
            sm += part3[(o * S3 + s) * 2];
            s2 += part3[(o * S3 + s) * 2 + 1];
        }
        float mean = sm * (1.f / 2048.f);
        float var = s2 * (1.f / 2048.f) - mean * mean;
        float rs = rsqrtf(var + 1e-5f);
        float scl = g3[o] * rs;
        float sh = b3[o] - mean * scl;
        const float* p = a4 + (b * 128 + o) * 4;
        float sv = p[0] + p[1] + p[2] + p[3];
        float pooled = fmaf(sv * 0.25f, scl, sh);
        acc = fmaf(pooled, fcw[o], acc);
    }
#pragma unroll
    for (int off = 32; off > 0; off >>= 1) acc += __shfl_down(acc, off);
    if (lane == 0) out[b] = 1.0f / (1.0f + expf(-(acc + fcb[0])));
}

extern "C" void kernel_launch(void* const* d_in, const int* in_sizes, int n_in,
                              void* d_out, int out_size, void* d_ws, size_t ws_size,
                              hipStream_t stream) {
    const float* x   = (const float*)d_in[0];
    const float* bw1 = (const float*)d_in[1];
    const float* sw1 = (const float*)d_in[2];
    const float* sc1 = (const float*)d_in[3];
    const float* bw2 = (const float*)d_in[4];
    const float* sw2 = (const float*)d_in[5];
    const float* sc2 = (const float*)d_in[6];
    const float* bw3 = (const float*)d_in[7];
    const float* sw3 = (const float*)d_in[8];
    const float* sc3 = (const float*)d_in[9];
    const float* bw4 = (const float*)d_in[10];
    const float* sw4 = (const float*)d_in[11];
    const float* sc4 = (const float*)d_in[12];
    const float* g1  = (const float*)d_in[13];
    const float* b1  = (const float*)d_in[14];
    const float* g2  = (const float*)d_in[15];
    const float* b2  = (const float*)d_in[16];
    const float* g3  = (const float*)d_in[17];
    const float* b3  = (const float*)d_in[18];
    const float* fcw = (const float*)d_in[19];
    const float* fcb = (const float*)d_in[20];

    float* ws = (float*)d_ws;
    float* a1 = ws;                    // 4194304 floats (dead after L2 -> P3)
    float* a2 = a1 + 4194304;          // 2097152 (dead after L3 -> P4)
    float* a3 = a2 + 2097152;          // 1048576
    float* a4 = a3 + 1048576;          // 262144
    unsigned short* wf1 = (unsigned short*)(a4 + 262144);  // 12288 ushorts
    unsigned short* wf2 = wf1 + 12288;      // 262144
    unsigned short* wf3 = wf2 + 262144;     // 1048576
    unsigned short* wf4 = wf3 + 1048576;    // 2097152
    float* part1 = (float*)(wf4 + 2097152); // 64*16*2  = 2048
    float* part2 = part1 + 2048;            // 128*16*2 = 4096
    float* part3 = part2 + 4096;            // 128*8*2  = 2048
    float* P3 = a1;                    // 4 * 8192*128 = 4194304 floats
    float* P4 = a2;                    // 8 * 2048*128 = 2097152 floats

    // weight prep: one fragment per thread (427520 frags)
    prep_all<<<1670, 256, 0, stream>>>(bw1, sw1, sc1, bw2, sw2, sc2,
                                       bw3, sw3, sc3, bw4, sw4, sc4,
                                       wf1, wf2, wf3, wf4);

    // L1: (512,3,32,32) -> (512,32,16,16), BM=256 (1 image), single phase UB=3
    kan_conv_fused<3, 32, 1, 16, 16, 4, 1, 4, 3, 3, false, 1, 1, false, 0>
        <<<512, 256, 0, stream>>>(x, wf1, nullptr, nullptr, nullptr, a1);
    // L2: -> (512,64,8,8), BM=128 (2 images), N-split 2, UB=4 (8 phases)
    kan_conv_fused<32, 64, 2, 8, 8, 4, 1, 2, 32, 4, false, 1, 1, false, 0>
        <<<dim3(256, 2), 256, 0, stream>>>(a1, wf2, nullptr, nullptr, nullptr, a2);
    bn_partial<64, 64, 16><<<1024, 256, 0, stream>>>(a2, part1);
    // L3: -> (512,128,4,4), BM=128 (8 images), N-split 2 x K-split 4x16ch,
    // UB=2, BN1 folded in-kernel
    kan_conv_fused<64, 128, 2, 4, 4, 4, 1, 2, 16, 2, true, 16, 32768, true, 1>
        <<<dim3(64, 8), 256, 0, stream>>>(a2, wf3, part1, g1, b1, P3);
    reduce_split<4, 128, 4, 4><<<1024, 256, 0, stream>>>(P3, a3);
    bn_partial<128, 16, 16><<<2048, 256, 0, stream>>>(a3, part2);
    // L4: -> (512,128,2,2), BM=64 (16 images), N-split 2 x K-split 8x16ch,
    // UB=2, BN2 folded in-kernel
    kan_conv_fused<128, 128, 2, 2, 2, 4, 1, 1, 16, 2, true, 16, 8192, true, 0>
        <<<dim3(32, 16), 256, 0, stream>>>(a3, wf4, part2, g2, b2, P4);
    reduce_split<8, 128, 2, 2><<<256, 256, 0, stream>>>(P4, a4);
    bn_partial<128, 4, 8><<<1024, 256, 0, stream>>>(a4, part3);
    // Head: BN3-finish + pool + FC + sigmoid
    head_ker<8><<<512, 64, 0, stream>>>(a4, part3, g3, b3, fcw, fcb, (float*)d_out);
}

// Round 13
// 131.756 us; speedup vs baseline: 1.5559x; 1.0445x over previous
//
#include <hip/hip_runtime.h>
#include <hip/hip_bf16.h>
#include <math.h>

#define DEVINL __device__ __forceinline__

typedef short short8 __attribute__((ext_vector_type(8)));
typedef float f32x4 __attribute__((ext_vector_type(4)));

DEVINL unsigned short f2bf(float f) {
    union { float f; unsigned int u; } c; c.f = f;
    unsigned int u = c.u;
    return (unsigned short)((u + 0x7fffu + ((u >> 16) & 1u)) >> 16);
}

DEVINL unsigned int packbf2(float a, float b) {
    union { __hip_bfloat162 h; unsigned int u; } c;
    c.h = __float22bfloat162_rn(make_float2(a, b));
    return c.u;  // a low 16, b high 16
}

DEVINL void gload_lds16(const unsigned int* g, unsigned int* l) {
    __builtin_amdgcn_global_load_lds((const __attribute__((address_space(1))) unsigned int*)g,
                                     (__attribute__((address_space(3))) unsigned int*)l, 16, 0, 0);
}

// Closed-form quadratic B-spline expansion, uniform extended grid
// (knots t_i=(i-2)*(2/3)-1): u=1.5x+3.5, j=floor(u), t=u-j.
// Frag = bf16x8 [relu(x), b0..b4, 0, 0].
DEVINL uint4 expand_frag(float v) {
    float relu = fmaxf(v, 0.f);
    float u = fmaf(v, 1.5f, 3.5f);
    float fj = floorf(u);
    int j = (int)fj;
    float t = u - fj;
    float omt = 1.f - t;
    float v2 = 0.5f * omt * omt;
    float v1 = fmaf(t, omt, 0.5f);
    float v0 = 0.5f * t * t;
    float b[5];
#pragma unroll
    for (int i = 0; i < 5; ++i)
        b[i] = (i == j) ? v0 : (i == j - 1) ? v1 : (i == j - 2) ? v2 : 0.f;
    uint4 r;
    r.x = packbf2(relu, b[0]);
    r.y = packbf2(b[1], b[2]);
    r.z = packbf2(b[3], b[4]);
    r.w = 0u;
    return r;
}

// ---- weight prep: one MFMA B-fragment (8 bf16) per thread ----
DEVINL void prep_frag(int fi, int F, int NTT, const float* __restrict__ bw,
                      const float* __restrict__ sw, const float* __restrict__ sc,
                      unsigned short* __restrict__ wf) {
    int lane = fi & 63;
    int t = fi >> 6;        // (c*NTT+nt)*4 + ks
    int ks = t & 3;
    int t2 = t >> 2;
    int nt = t2 % NTT;
    int c = t2 / NTT;
    int tap = ks * 4 + (lane >> 4);
    int f = c * 16 + tap;
    int o = nt * 16 + (lane & 15);
    float scv = sc[o * F + f];
    float b = bw[o * F + f];
    float s0 = sw[(o * F + f) * 5 + 0] * scv;
    float s1 = sw[(o * F + f) * 5 + 1] * scv;
    float s2 = sw[(o * F + f) * 5 + 2] * scv;
    float s3 = sw[(o * F + f) * 5 + 3] * scv;
    float s4 = sw[(o * F + f) * 5 + 4] * scv;
    uint4 r;
    r.x = packbf2(b, s0);
    r.y = packbf2(s1, s2);
    r.z = packbf2(s3, s4);
    r.w = 0u;
    *(uint4*)&wf[(size_t)fi * 8] = r;
}

__global__ __launch_bounds__(256) void prep_all(
    const float* __restrict__ bw1, const float* __restrict__ sw1, const float* __restrict__ sc1,
    const float* __restrict__ bw2, const float* __restrict__ sw2, const float* __restrict__ sc2,
    const float* __restrict__ bw3, const float* __restrict__ sw3, const float* __restrict__ sc3,
    const float* __restrict__ bw4, const float* __restrict__ sw4, const float* __restrict__ sc4,
    unsigned short* __restrict__ wf1, unsigned short* __restrict__ wf2,
    unsigned short* __restrict__ wf3, unsigned short* __restrict__ wf4) {
    int fi = blockIdx.x * 256 + threadIdx.x;
    const int N1 = 3 * 32 * 16;           // 1536 frags
    const int N2 = 32 * 64 * 16;          // 32768
    const int N3 = 64 * 128 * 16;         // 131072
    const int N4 = 128 * 128 * 16;        // 262144
    if (fi < N1) prep_frag(fi, 48, 2, bw1, sw1, sc1, wf1);
    else if (fi < N1 + N2) prep_frag(fi - N1, 512, 4, bw2, sw2, sc2, wf2);
    else if (fi < N1 + N2 + N3) prep_frag(fi - N1 - N2, 1024, 8, bw3, sw3, sc3, wf3);
    else if (fi < N1 + N2 + N3 + N4) prep_frag(fi - N1 - N2 - N3, 2048, 8, bw4, sw4, sc4, wf4);
}

// ---- fused KAN conv (round-7 phased structure: the proven best) ----
// Per phase: stage UB channels' B frags (global_load_lds) + expand UB
// channels' input tiles into LDS -> one barrier -> UB*4 MFMA k-steps ->
// barrier. BN path: BNS==1 reads finalized scale/shift from part directly;
// BNS>1 folds partials. BN NOT applied to padding zeros (pad taps read slot
// 0 = expansion of v=0).
template <int CIN, int COUTT, int NSP, int HOUT, int WOUT, int WM, int WN, int MT,
          int CPS, int UB, bool HASBN, int BNS, int NBN, bool SPLITOUT, int RPAD>
__global__ __launch_bounds__(256) void kan_conv_fused(
    const float* __restrict__ in, const unsigned short* __restrict__ wf,
    const float* __restrict__ part, const float* __restrict__ gamma,
    const float* __restrict__ beta, float* __restrict__ out) {
    constexpr int HIN = HOUT * 2, WIN = WOUT * 2, W2 = WOUT;
    constexpr int COUT = COUTT / NSP;       // this block's N extent
    constexpr int NTT = COUTT / 16;
    constexpr int NT = COUT / 16;
    constexpr int NTW = NT / WN;
    constexpr int BM = WM * MT * 16;
    constexpr int IMG_POS = HOUT * WOUT;
    constexpr int NIMG = BM / IMG_POS;
    constexpr int RS = WIN + RPAD;
    constexpr int IMG_STRIDE = HIN * RS + 1;
    constexpr int ASLOTS = NIMG * IMG_STRIDE + 1;  // slot 0 = pad frag
    constexpr int M_TOT = 512 * IMG_POS;
    constexpr int EV = NIMG * HIN * WIN;
    constexpr int EITER = (EV + 255) / 256;
    static_assert(WM * WN == 4, "4 waves");
    static_assert(CPS % UB == 0, "UB divides CPS");

    __shared__ uint4 A_e[UB][ASLOTS];
    __shared__ uint4 B_l[UB][COUT * 16];

    const int tid = threadIdx.x;
    const int lane = tid & 63;
    const int w = tid >> 6;
    const int wm = w % WM;
    const int wn = w / WM;
    const int g = lane >> 4;        // kw
    const int r16 = lane & 15;
    const int m0 = blockIdx.x * BM;
    const int b0 = m0 / IMG_POS;
    const int nh = (NSP > 1) ? ((int)blockIdx.y % NSP) : 0;
    const int kslice = (NSP > 1) ? ((int)blockIdx.y / NSP) : (SPLITOUT ? (int)blockIdx.y : 0);
    const int c0 = SPLITOUT ? kslice * CPS : 0;

    // Per-mt fragment geometry (channel-invariant).
    int aoff[MT];
    int vmask = 0;
#pragma unroll
    for (int mt = 0; mt < MT; ++mt) {
        int p = (wm * MT + mt) * 16 + r16;
        int m = m0 + p;
        int ow = m % WOUT;
        int oh = (m / WOUT) % HOUT;
        int bl = p / IMG_POS;
        int iw = 2 * ow - 1 + g;
        bool iv = (iw >= 0) && (iw < WIN);
        aoff[mt] = 1 + bl * IMG_STRIDE + (2 * oh) * RS + (iw & 1) * W2 + (iw >> 1);
#pragma unroll
        for (int ks = 0; ks < 4; ++ks) {
            bool vv = iv && !(oh == 0 && ks == 0) && !(oh == HOUT - 1 && ks == 3);
            vmask |= (vv ? 1 : 0) << (mt * 4 + ks);
        }
    }

    if (tid < UB) A_e[tid][0] = expand_frag(0.f);  // pad slots, covered by 1st barrier

    f32x4 acc[MT][NTW];
#pragma unroll
    for (int mt = 0; mt < MT; ++mt)
#pragma unroll
        for (int n = 0; n < NTW; ++n) acc[mt][n] = f32x4{0.f, 0.f, 0.f, 0.f};

    for (int cc = 0; cc < CPS; cc += UB) {
        // (1) issue all B staging for the UB channels (in flight during (2))
#pragma unroll
        for (int u = 0; u < UB; ++u) {
            const int ch = c0 + cc + u;
            const unsigned int* bsrc = (const unsigned int*)wf + ((size_t)ch * NTT + nh * NT) * 1024;
            unsigned int* bdst = (unsigned int*)&B_l[u][0];
#pragma unroll
            for (int r2 = 0; r2 < NT; ++r2)
                gload_lds16(bsrc + (r2 << 10) + tid * 4, bdst + (r2 << 10) + tid * 4);
        }
        // (2) expand UB channels' tiles (once per element); BN folded
#pragma unroll
        for (int u = 0; u < UB; ++u) {
            const int ch = c0 + cc + u;
            float bsc = 1.f, bsh = 0.f;
            if (HASBN) {
                if constexpr (BNS == 1) {  // finalized scale/shift
                    bsc = part[ch * 2];
                    bsh = part[ch * 2 + 1];
                } else {                   // uniform scalar reduction of partials
                    float sm = 0.f, s2 = 0.f;
#pragma unroll 4
                    for (int s = 0; s < BNS; ++s) {
                        sm += part[(ch * BNS + s) * 2];
                        s2 += part[(ch * BNS + s) * 2 + 1];
                    }
                    const float invN = 1.f / (float)NBN;
                    float mean = sm * invN;
                    float var = s2 * invN - mean * mean;
                    float rs = rsqrtf(var + 1e-5f);
                    bsc = gamma[ch] * rs;
                    bsh = beta[ch] - mean * bsc;
                }
            }
#pragma unroll
            for (int ii = 0; ii < EITER; ++ii) {
                int e = tid + ii * 256;
                if ((EV % 256 == 0) || e < EV) {
                    int bl = e / (HIN * WIN);
                    int r = e - bl * (HIN * WIN);
                    int ih = r / WIN;
                    int iw = r - ih * WIN;
                    float v = in[(((size_t)(b0 + bl) * CIN + ch) * HIN + ih) * WIN + iw];
                    if (HASBN) v = fmaf(v, bsc, bsh);
                    A_e[u][1 + bl * IMG_STRIDE + ih * RS + (iw & 1) * W2 + (iw >> 1)] = expand_frag(v);
                }
            }
        }
        __syncthreads();  // drains gload_lds (vmcnt) + ds_writes (lgkm)
        // (3) MFMA: UB x 4 k-steps x MT x NTW
#pragma unroll
        for (int u = 0; u < UB; ++u) {
#pragma unroll
            for (int ks = 0; ks < 4; ++ks) {
                short8 bf[NTW];
#pragma unroll
                for (int n = 0; n < NTW; ++n)
                    bf[n] = *(const short8*)&B_l[u][(((wn * NTW + n) * 4 + ks) << 6) + lane];
#pragma unroll
                for (int mt = 0; mt < MT; ++mt) {
                    int slot = ((vmask >> (mt * 4 + ks)) & 1) ? (aoff[mt] + (ks - 1) * RS) : 0;
                    short8 af = *(const short8*)&A_e[u][slot];
#pragma unroll
                    for (int n = 0; n < NTW; ++n)
                        acc[mt][n] = __builtin_amdgcn_mfma_f32_16x16x32_bf16(af, bf[n], acc[mt][n], 0, 0, 0);
                }
            }
        }
        __syncthreads();  // buffers reused next phase
    }

    // Epilogue. D mapping: col=lane&15, row=(lane>>4)*4+reg [m89].
    const int colo = lane & 15;
    const int row4 = (lane >> 4) * 4;
#pragma unroll
    for (int mt = 0; mt < MT; ++mt) {
#pragma unroll
        for (int n = 0; n < NTW; ++n) {
            int o = nh * COUT + (wn * NTW + n) * 16 + colo;
#pragma unroll
            for (int rr = 0; rr < 4; ++rr) {
                int p = (wm * MT + mt) * 16 + row4 + rr;
                int m = m0 + p;
                if (SPLITOUT) {
                    out[((size_t)kslice * M_TOT + m) * COUTT + o] = acc[mt][n][rr];
                } else {
                    int ow = m % WOUT;
                    int t = m / WOUT;
                    int oh = t % HOUT;
                    int b = t / HOUT;
                    out[((b * COUTT + o) * HOUT + oh) * WOUT + ow] = acc[mt][n][rr];
                }
            }
        }
    }
}

// ---- fused split-K reduce + BN partial stats (full grid: 1 elem/thread) ----
// NB*256*4 == M*COUT exactly. Per-thread channel set constant; per-block
// partials via deterministic LDS histogram.
template <int NS, int COUT, int HOUT, int WOUT, int NB>
__global__ __launch_bounds__(256) void reduce_bn(const float* __restrict__ P,
                                                 float* __restrict__ out,
                                                 float* __restrict__ part) {
    constexpr int M = 512 * HOUT * WOUT;
    static_assert(COUT == 128, "LDS reduce assumes 128 channels");
    static_assert(NB * 256 * 4 == M * COUT, "exact cover");
    const int tid = threadIdx.x;
    const int idx4 = blockIdx.x * 256 + tid;
    f32x4 s = {0.f, 0.f, 0.f, 0.f};
#pragma unroll
    for (int i = 0; i < NS; ++i)
        s += *(const f32x4*)&P[(size_t)i * M * COUT + (size_t)idx4 * 4];
    int o0 = (idx4 * 4) % COUT;
    int m = (idx4 * 4) / COUT;
    int ow = m % WOUT;
    int t = m / WOUT;
    int oh = t % HOUT;
    int b = t / HOUT;
    float sm[4], sq[4];
#pragma unroll
    for (int q = 0; q < 4; ++q) {
        out[((b * COUT + o0 + q) * HOUT + oh) * WOUT + ow] = s[q];
        sm[q] = s[q];
        sq[q] = s[q] * s[q];
    }
    __shared__ float red[2][COUT][8];
    int gch = tid & 31, h = tid >> 5;   // channel group (o0/4), 8 threads each
#pragma unroll
    for (int q = 0; q < 4; ++q) {
        red[0][gch * 4 + q][h] = sm[q];
        red[1][gch * 4 + q][h] = sq[q];
    }
    __syncthreads();
    int st = tid >> 7;   // 0=sum, 1=sumsq
    int c = tid & 127;
    float v = 0.f;
#pragma unroll
    for (int k = 0; k < 8; ++k) v += red[st][c][k];
    part[((size_t)c * NB + blockIdx.x) * 2 + st] = v;
}

// Finalize BN: reduce NB per-block partials -> scale/shift per channel.
template <int NB, int NBN>
__global__ __launch_bounds__(256) void bn_finish(const float* __restrict__ part,
                                                 const float* __restrict__ gamma,
                                                 const float* __restrict__ beta,
                                                 float* __restrict__ fin) {
    int c = blockIdx.x;
    int tid = threadIdx.x;
    float sm = 0.f, s2 = 0.f;
    for (int i = tid; i < NB; i += 256) {
        sm += part[((size_t)c * NB + i) * 2];
        s2 += part[((size_t)c * NB + i) * 2 + 1];
    }
    __shared__ float r0[256], r1[256];
    r0[tid] = sm; r1[tid] = s2;
    __syncthreads();
    for (int off = 128; off > 0; off >>= 1) {
        if (tid < off) { r0[tid] += r0[tid + off]; r1[tid] += r1[tid + off]; }
        __syncthreads();
    }
    if (tid == 0) {
        const float invN = 1.f / (float)NBN;
        float mean = r0[0] * invN;
        float var = r1[0] * invN - mean * mean;
        float rs = rsqrtf(var + 1e-5f);
        float scl = gamma[c] * rs;
        fin[c * 2] = scl;
        fin[c * 2 + 1] = beta[c] - mean * scl;
    }
}

// BN stage 1 (L2 output a2, NCHW): block (c,s), float4 reads.
template <int C, int HW, int S>
__global__ __launch_bounds__(256) void bn_partial(const float* __restrict__ a,
                                                  float* __restrict__ part) {
    constexpr int BS = 512 / S;
    constexpr int H4 = HW / 4;
    int c = blockIdx.x / S, s = blockIdx.x % S;
    int tid = threadIdx.x;
    float sm = 0.f, s2 = 0.f;
    for (int i = tid; i < BS * H4; i += 256) {
        int b = i / H4, r = i - (i / H4) * H4;
        f32x4 v = *(const f32x4*)&a[(((size_t)(s * BS + b) * C + c) * HW) + r * 4];
#pragma unroll
        for (int q = 0; q < 4; ++q) { sm += v[q]; s2 += v[q] * v[q]; }
    }
    __shared__ float r0[256], r1[256];
    r0[tid] = sm; r1[tid] = s2;
    __syncthreads();
    for (int off = 128; off > 0; off >>= 1) {
        if (tid < off) { r0[tid] += r0[tid + off]; r1[tid] += r1[tid + off]; }
        __syncthreads();
    }
    if (tid == 0) {
        part[(c * S + s) * 2] = r0[0];
        part[(c * S + s) * 2 + 1] = r1[0];
    }
}

// BN3 (finalized) + avgpool(2x2) + FC(128->1) + sigmoid. One wave per batch.
__global__ void head_ker(const float* __restrict__ a4, const float* __restrict__ fin3,
                         const float* __restrict__ fcw, const float* __restrict__ fcb,
                         float* __restrict__ out) {
    int b = blockIdx.x;
    int lane = threadIdx.x;  // 64
    float acc = 0.0f;
#pragma unroll
    for (int j = 0; j < 2; ++j) {
        int o = lane + 64 * j;
        float scl = fin3[o * 2];
        float sh = fin3[o * 2 + 1];
        const float* p = a4 + (b * 128 + o) * 4;
        float sv = p[0] + p[1] + p[2] + p[3];
        float pooled = fmaf(sv * 0.25f, scl, sh);
        acc = fmaf(pooled, fcw[o], acc);
    }
#pragma unroll
    for (int off = 32; off > 0; off >>= 1) acc += __shfl_down(acc, off);
    if (lane == 0) out[b] = 1.0f / (1.0f + expf(-(acc + fcb[0])));
}

extern "C" void kernel_launch(void* const* d_in, const int* in_sizes, int n_in,
                              void* d_out, int out_size, void* d_ws, size_t ws_size,
                              hipStream_t stream) {
    const float* x   = (const float*)d_in[0];
    const float* bw1 = (const float*)d_in[1];
    const float* sw1 = (const float*)d_in[2];
    const float* sc1 = (const float*)d_in[3];
    const float* bw2 = (const float*)d_in[4];
    const float* sw2 = (const float*)d_in[5];
    const float* sc2 = (const float*)d_in[6];
    const float* bw3 = (const float*)d_in[7];
    const float* sw3 = (const float*)d_in[8];
    const float* sc3 = (const float*)d_in[9];
    const float* bw4 = (const float*)d_in[10];
    const float* sw4 = (const float*)d_in[11];
    const float* sc4 = (const float*)d_in[12];
    const float* g1  = (const float*)d_in[13];
    const float* b1  = (const float*)d_in[14];
    const float* g2  = (const float*)d_in[15];
    const float* b2  = (const float*)d_in[16];
    const float* g3  = (const float*)d_in[17];
    const float* b3  = (const float*)d_in[18];
    const float* fcw = (const float*)d_in[19];
    const float* fcb = (const float*)d_in[20];

    float* ws = (float*)d_ws;
    float* a1 = ws;                    // 4194304 floats (dead after L2 -> P3)
    float* a2 = a1 + 4194304;          // 2097152 (dead after L3 -> P4)
    float* a3 = a2 + 2097152;          // 1048576
    float* a4 = a3 + 1048576;          // 262144
    unsigned short* wf1 = (unsigned short*)(a4 + 262144);  // 12288 ushorts
    unsigned short* wf2 = wf1 + 12288;      // 262144
    unsigned short* wf3 = wf2 + 262144;     // 1048576
    unsigned short* wf4 = wf3 + 1048576;    // 2097152
    float* part1 = (float*)(wf4 + 2097152); // 64*16*2   = 2048
    float* part2 = part1 + 2048;            // 128*1024*2 = 262144
    float* part3 = part2 + 262144;          // 128*256*2  = 65536
    float* fin2  = part3 + 65536;           // 128*2 = 256
    float* fin3  = fin2 + 256;              // 128*2 = 256
    float* P3 = a1;                    // 4 * 8192*128 = 4194304 floats
    float* P4 = a2;                    // 8 * 2048*128 = 2097152 floats

    // weight prep: one fragment per thread (427520 frags)
    prep_all<<<1670, 256, 0, stream>>>(bw1, sw1, sc1, bw2, sw2, sc2,
                                       bw3, sw3, sc3, bw4, sw4, sc4,
                                       wf1, wf2, wf3, wf4);

    // L1: (512,3,32,32) -> (512,32,16,16), BM=256 (1 image), single phase UB=3
    kan_conv_fused<3, 32, 1, 16, 16, 4, 1, 4, 3, 3, false, 1, 1, false, 0>
        <<<512, 256, 0, stream>>>(x, wf1, nullptr, nullptr, nullptr, a1);
    // L2: -> (512,64,8,8), BM=128 (2 images), N-split 2, UB=4 (8 phases)
    kan_conv_fused<32, 64, 2, 8, 8, 4, 1, 2, 32, 4, false, 1, 1, false, 0>
        <<<dim3(256, 2), 256, 0, stream>>>(a1, wf2, nullptr, nullptr, nullptr, a2);
    bn_partial<64, 64, 16><<<1024, 256, 0, stream>>>(a2, part1);
    // L3: -> (512,128,4,4), BM=128 (8 images), N-split 2 x K-split 4x16ch,
    // UB=2, BN1 folded in-kernel (BNS=16 partials)
    kan_conv_fused<64, 128, 2, 4, 4, 4, 1, 2, 16, 2, true, 16, 32768, true, 1>
        <<<dim3(64, 8), 256, 0, stream>>>(a2, wf3, part1, g1, b1, P3);
    // fused reduce(P3 -> a3) + BN2 block partials (full 1024-block grid)
    reduce_bn<4, 128, 4, 4, 1024><<<1024, 256, 0, stream>>>(P3, a3, part2);
    bn_finish<1024, 8192><<<128, 256, 0, stream>>>(part2, g2, b2, fin2);
    // L4: -> (512,128,2,2), BM=64 (16 images), N-split 2 x K-split 8x16ch,
    // UB=2, BN2 finalized (BNS=1 direct scale/shift)
    kan_conv_fused<128, 128, 2, 2, 2, 4, 1, 1, 16, 2, true, 1, 1, true, 0>
        <<<dim3(32, 16), 256, 0, stream>>>(a3, wf4, fin2, nullptr, nullptr, P4);
    // fused reduce(P4 -> a4) + BN3 block partials (full 256-block grid)
    reduce_bn<8, 128, 2, 2, 256><<<256, 256, 0, stream>>>(P4, a4, part3);
    bn_finish<256, 2048><<<128, 256, 0, stream>>>(part3, g3, b3, fin3);
    // Head: BN3 (finalized) + pool + FC + sigmoid
    head_ker<<<512, 64, 0, stream>>>(a4, fin3, fcw, fcb, (float*)d_out);
}

// Round 14
// 123.510 us; speedup vs baseline: 1.6597x; 1.0668x over previous
//
#include <hip/hip_runtime.h>
#include <hip/hip_bf16.h>
#include <math.h>

#define DEVINL __device__ __forceinline__

typedef short short8 __attribute__((ext_vector_type(8)));
typedef float f32x4 __attribute__((ext_vector_type(4)));

DEVINL unsigned short f2bf(float f) {
    union { float f; unsigned int u; } c; c.f = f;
    unsigned int u = c.u;
    return (unsigned short)((u + 0x7fffu + ((u >> 16) & 1u)) >> 16);
}

DEVINL unsigned int packbf2(float a, float b) {
    union { __hip_bfloat162 h; unsigned int u; } c;
    c.h = __float22bfloat162_rn(make_float2(a, b));
    return c.u;  // a low 16, b high 16
}

DEVINL void gload_lds16(const unsigned int* g, unsigned int* l) {
    __builtin_amdgcn_global_load_lds((const __attribute__((address_space(1))) unsigned int*)g,
                                     (__attribute__((address_space(3))) unsigned int*)l, 16, 0, 0);
}

// Closed-form quadratic B-spline expansion, uniform extended grid
// (knots t_i=(i-2)*(2/3)-1): u=1.5x+3.5, j=floor(u), t=u-j.
// Frag = bf16x8 [relu(x), b0..b4, 0, 0].
DEVINL uint4 expand_frag(float v) {
    float relu = fmaxf(v, 0.f);
    float u = fmaf(v, 1.5f, 3.5f);
    float fj = floorf(u);
    int j = (int)fj;
    float t = u - fj;
    float omt = 1.f - t;
    float v2 = 0.5f * omt * omt;
    float v1 = fmaf(t, omt, 0.5f);
    float v0 = 0.5f * t * t;
    float b[5];
#pragma unroll
    for (int i = 0; i < 5; ++i)
        b[i] = (i == j) ? v0 : (i == j - 1) ? v1 : (i == j - 2) ? v2 : 0.f;
    uint4 r;
    r.x = packbf2(relu, b[0]);
    r.y = packbf2(b[1], b[2]);
    r.z = packbf2(b[3], b[4]);
    r.w = 0u;
    return r;
}

// ---- weight prep: one MFMA B-fragment (8 bf16) per thread ----
DEVINL void prep_frag(int fi, int F, int NTT, const float* __restrict__ bw,
                      const float* __restrict__ sw, const float* __restrict__ sc,
                      unsigned short* __restrict__ wf) {
    int lane = fi & 63;
    int t = fi >> 6;        // (c*NTT+nt)*4 + ks
    int ks = t & 3;
    int t2 = t >> 2;
    int nt = t2 % NTT;
    int c = t2 / NTT;
    int tap = ks * 4 + (lane >> 4);
    int f = c * 16 + tap;
    int o = nt * 16 + (lane & 15);
    float scv = sc[o * F + f];
    float b = bw[o * F + f];
    float s0 = sw[(o * F + f) * 5 + 0] * scv;
    float s1 = sw[(o * F + f) * 5 + 1] * scv;
    float s2 = sw[(o * F + f) * 5 + 2] * scv;
    float s3 = sw[(o * F + f) * 5 + 3] * scv;
    float s4 = sw[(o * F + f) * 5 + 4] * scv;
    uint4 r;
    r.x = packbf2(b, s0);
    r.y = packbf2(s1, s2);
    r.z = packbf2(s3, s4);
    r.w = 0u;
    *(uint4*)&wf[(size_t)fi * 8] = r;
}

__global__ __launch_bounds__(256) void prep_all(
    const float* __restrict__ bw1, const float* __restrict__ sw1, const float* __restrict__ sc1,
    const float* __restrict__ bw2, const float* __restrict__ sw2, const float* __restrict__ sc2,
    const float* __restrict__ bw3, const float* __restrict__ sw3, const float* __restrict__ sc3,
    const float* __restrict__ bw4, const float* __restrict__ sw4, const float* __restrict__ sc4,
    unsigned short* __restrict__ wf1, unsigned short* __restrict__ wf2,
    unsigned short* __restrict__ wf3, unsigned short* __restrict__ wf4) {
    int fi = blockIdx.x * 256 + threadIdx.x;
    const int N1 = 3 * 32 * 16;           // 1536 frags
    const int N2 = 32 * 64 * 16;          // 32768
    const int N3 = 64 * 128 * 16;         // 131072
    const int N4 = 128 * 128 * 16;        // 262144
    if (fi < N1) prep_frag(fi, 48, 2, bw1, sw1, sc1, wf1);
    else if (fi < N1 + N2) prep_frag(fi - N1, 512, 4, bw2, sw2, sc2, wf2);
    else if (fi < N1 + N2 + N3) prep_frag(fi - N1 - N2, 1024, 8, bw3, sw3, sc3, wf3);
    else if (fi < N1 + N2 + N3 + N4) prep_frag(fi - N1 - N2 - N3, 2048, 8, bw4, sw4, sc4, wf4);
}

// ---- fused KAN conv (round-7 phased structure: the proven best) ----
// Per phase: stage UB channels' B frags (global_load_lds) + expand UB
// channels' input tiles into LDS -> one barrier -> UB*4 MFMA k-steps ->
// barrier. BN path: BNS==1 reads finalized scale/shift; BNS>1 folds
// partials. BN NOT applied to padding zeros (pad taps read slot 0 =
// expansion of v=0). STATS: epilogue also emits per-(channel,block) BN
// partial sums (deterministic LDS histogram; requires WN==1).
template <int CIN, int COUTT, int NSP, int HOUT, int WOUT, int WM, int WN, int MT,
          int CPS, int UB, bool HASBN, int BNS, int NBN, bool SPLITOUT, int RPAD,
          bool STATS = false>
__global__ __launch_bounds__(256) void kan_conv_fused(
    const float* __restrict__ in, const unsigned short* __restrict__ wf,
    const float* __restrict__ part, const float* __restrict__ gamma,
    const float* __restrict__ beta, float* __restrict__ out,
    float* __restrict__ statout) {
    constexpr int HIN = HOUT * 2, WIN = WOUT * 2, W2 = WOUT;
    constexpr int COUT = COUTT / NSP;       // this block's N extent
    constexpr int NTT = COUTT / 16;
    constexpr int NT = COUT / 16;
    constexpr int NTW = NT / WN;
    constexpr int BM = WM * MT * 16;
    constexpr int IMG_POS = HOUT * WOUT;
    constexpr int NIMG = BM / IMG_POS;
    constexpr int RS = WIN + RPAD;
    constexpr int IMG_STRIDE = HIN * RS + 1;
    constexpr int ASLOTS = NIMG * IMG_STRIDE + 1;  // slot 0 = pad frag
    constexpr int M_TOT = 512 * IMG_POS;
    constexpr int EV = NIMG * HIN * WIN;
    constexpr int EITER = (EV + 255) / 256;
    static_assert(WM * WN == 4, "4 waves");
    static_assert(CPS % UB == 0, "UB divides CPS");
    static_assert(!STATS || WN == 1, "stats assumes WN==1 (16 contributors/channel)");
    static_assert(!STATS || 2 * COUT <= 256, "stats reduce fits one block");

    __shared__ uint4 A_e[UB][ASLOTS];
    __shared__ uint4 B_l[UB][COUT * 16];

    const int tid = threadIdx.x;
    const int lane = tid & 63;
    const int w = tid >> 6;
    const int wm = w % WM;
    const int wn = w / WM;
    const int g = lane >> 4;        // kw
    const int r16 = lane & 15;
    const int m0 = blockIdx.x * BM;
    const int b0 = m0 / IMG_POS;
    const int nh = (NSP > 1) ? ((int)blockIdx.y % NSP) : 0;
    const int kslice = (NSP > 1) ? ((int)blockIdx.y / NSP) : (SPLITOUT ? (int)blockIdx.y : 0);
    const int c0 = SPLITOUT ? kslice * CPS : 0;

    // Per-mt fragment geometry (channel-invariant).
    int aoff[MT];
    int vmask = 0;
#pragma unroll
    for (int mt = 0; mt < MT; ++mt) {
        int p = (wm * MT + mt) * 16 + r16;
        int m = m0 + p;
        int ow = m % WOUT;
        int oh = (m / WOUT) % HOUT;
        int bl = p / IMG_POS;
        int iw = 2 * ow - 1 + g;
        bool iv = (iw >= 0) && (iw < WIN);
        aoff[mt] = 1 + bl * IMG_STRIDE + (2 * oh) * RS + (iw & 1) * W2 + (iw >> 1);
#pragma unroll
        for (int ks = 0; ks < 4; ++ks) {
            bool vv = iv && !(oh == 0 && ks == 0) && !(oh == HOUT - 1 && ks == 3);
            vmask |= (vv ? 1 : 0) << (mt * 4 + ks);
        }
    }

    if (tid < UB) A_e[tid][0] = expand_frag(0.f);  // pad slots, covered by 1st barrier

    f32x4 acc[MT][NTW];
#pragma unroll
    for (int mt = 0; mt < MT; ++mt)
#pragma unroll
        for (int n = 0; n < NTW; ++n) acc[mt][n] = f32x4{0.f, 0.f, 0.f, 0.f};

    for (int cc = 0; cc < CPS; cc += UB) {
        // (1) issue all B staging for the UB channels (in flight during (2))
#pragma unroll
        for (int u = 0; u < UB; ++u) {
            const int ch = c0 + cc + u;
            const unsigned int* bsrc = (const unsigned int*)wf + ((size_t)ch * NTT + nh * NT) * 1024;
            unsigned int* bdst = (unsigned int*)&B_l[u][0];
#pragma unroll
            for (int r2 = 0; r2 < NT; ++r2)
                gload_lds16(bsrc + (r2 << 10) + tid * 4, bdst + (r2 << 10) + tid * 4);
        }
        // (2) expand UB channels' tiles (once per element); BN folded
#pragma unroll
        for (int u = 0; u < UB; ++u) {
            const int ch = c0 + cc + u;
            float bsc = 1.f, bsh = 0.f;
            if (HASBN) {
                if constexpr (BNS == 1) {  // finalized scale/shift
                    bsc = part[ch * 2];
                    bsh = part[ch * 2 + 1];
                } else {                   // uniform scalar reduction of partials
                    float sm = 0.f, s2 = 0.f;
#pragma unroll 4
                    for (int s = 0; s < BNS; ++s) {
                        sm += part[(ch * BNS + s) * 2];
                        s2 += part[(ch * BNS + s) * 2 + 1];
                    }
                    const float invN = 1.f / (float)NBN;
                    float mean = sm * invN;
                    float var = s2 * invN - mean * mean;
                    float rs = rsqrtf(var + 1e-5f);
                    bsc = gamma[ch] * rs;
                    bsh = beta[ch] - mean * bsc;
                }
            }
#pragma unroll
            for (int ii = 0; ii < EITER; ++ii) {
                int e = tid + ii * 256;
                if ((EV % 256 == 0) || e < EV) {
                    int bl = e / (HIN * WIN);
                    int r = e - bl * (HIN * WIN);
                    int ih = r / WIN;
                    int iw = r - ih * WIN;
                    float v = in[(((size_t)(b0 + bl) * CIN + ch) * HIN + ih) * WIN + iw];
                    if (HASBN) v = fmaf(v, bsc, bsh);
                    A_e[u][1 + bl * IMG_STRIDE + ih * RS + (iw & 1) * W2 + (iw >> 1)] = expand_frag(v);
                }
            }
        }
        __syncthreads();  // drains gload_lds (vmcnt) + ds_writes (lgkm)
        // (3) MFMA: UB x 4 k-steps x MT x NTW
#pragma unroll
        for (int u = 0; u < UB; ++u) {
#pragma unroll
            for (int ks = 0; ks < 4; ++ks) {
                short8 bf[NTW];
#pragma unroll
                for (int n = 0; n < NTW; ++n)
                    bf[n] = *(const short8*)&B_l[u][(((wn * NTW + n) * 4 + ks) << 6) + lane];
#pragma unroll
                for (int mt = 0; mt < MT; ++mt) {
                    int slot = ((vmask >> (mt * 4 + ks)) & 1) ? (aoff[mt] + (ks - 1) * RS) : 0;
                    short8 af = *(const short8*)&A_e[u][slot];
#pragma unroll
                    for (int n = 0; n < NTW; ++n)
                        acc[mt][n] = __builtin_amdgcn_mfma_f32_16x16x32_bf16(af, bf[n], acc[mt][n], 0, 0, 0);
                }
            }
        }
        __syncthreads();  // buffers reused next phase
    }

    // Epilogue. D mapping: col=lane&15, row=(lane>>4)*4+reg [m89].
    const int colo = lane & 15;
    const int row4 = (lane >> 4) * 4;
#pragma unroll
    for (int mt = 0; mt < MT; ++mt) {
#pragma unroll
        for (int n = 0; n < NTW; ++n) {
            int o = nh * COUT + (wn * NTW + n) * 16 + colo;
#pragma unroll
            for (int rr = 0; rr < 4; ++rr) {
                int p = (wm * MT + mt) * 16 + row4 + rr;
                int m = m0 + p;
                if (SPLITOUT) {
                    out[((size_t)kslice * M_TOT + m) * COUTT + o] = acc[mt][n][rr];
                } else {
                    int ow = m % WOUT;
                    int t = m / WOUT;
                    int oh = t % HOUT;
                    int b = t / HOUT;
                    out[((b * COUTT + o) * HOUT + oh) * WOUT + ow] = acc[mt][n][rr];
                }
            }
        }
    }

    // STATS epilogue: per-channel sum/sumsq over this block's BM positions.
    // Per channel o: 16 contributors (4 waves x 4 row-groups), each summing
    // its MT*4 values. LDS reads all done (last loop barrier) -> reuse A_e.
    if constexpr (STATS) {
        float* red = (float*)&A_e[0][0];   // [2][COUT][16] floats
        const int contrib = wm * 4 + (lane >> 4);
#pragma unroll
        for (int n = 0; n < NTW; ++n) {
            float ls = 0.f, ls2 = 0.f;
#pragma unroll
            for (int mt = 0; mt < MT; ++mt)
#pragma unroll
                for (int rr = 0; rr < 4; ++rr) {
                    float v = acc[mt][n][rr];
                    ls += v;
                    ls2 += v * v;
                }
            int o = n * 16 + colo;
            red[o * 16 + contrib] = ls;
            red[(COUT + o) * 16 + contrib] = ls2;
        }
        __syncthreads();
        if (tid < 2 * COUT) {
            int st = tid / COUT, o = tid % COUT;
            float v = 0.f;
#pragma unroll
            for (int k = 0; k < 16; ++k) v += red[(st * COUT + o) * 16 + k];
            statout[(((size_t)(nh * COUT + o)) * gridDim.x + blockIdx.x) * 2 + st] = v;
        }
    }
}

// ---- fused split-K reduce + BN partial stats (full grid: 1 elem/thread) ----
template <int NS, int COUT, int HOUT, int WOUT, int NB>
__global__ __launch_bounds__(256) void reduce_bn(const float* __restrict__ P,
                                                 float* __restrict__ out,
                                                 float* __restrict__ part) {
    constexpr int M = 512 * HOUT * WOUT;
    static_assert(COUT == 128, "LDS reduce assumes 128 channels");
    static_assert(NB * 256 * 4 == M * COUT, "exact cover");
    const int tid = threadIdx.x;
    const int idx4 = blockIdx.x * 256 + tid;
    f32x4 s = {0.f, 0.f, 0.f, 0.f};
#pragma unroll
    for (int i = 0; i < NS; ++i)
        s += *(const f32x4*)&P[(size_t)i * M * COUT + (size_t)idx4 * 4];
    int o0 = (idx4 * 4) % COUT;
    int m = (idx4 * 4) / COUT;
    int ow = m % WOUT;
    int t = m / WOUT;
    int oh = t % HOUT;
    int b = t / HOUT;
    float sm[4], sq[4];
#pragma unroll
    for (int q = 0; q < 4; ++q) {
        out[((b * COUT + o0 + q) * HOUT + oh) * WOUT + ow] = s[q];
        sm[q] = s[q];
        sq[q] = s[q] * s[q];
    }
    __shared__ float red[2][COUT][8];
    int gch = tid & 31, h = tid >> 5;   // channel group (o0/4), 8 threads each
#pragma unroll
    for (int q = 0; q < 4; ++q) {
        red[0][gch * 4 + q][h] = sm[q];
        red[1][gch * 4 + q][h] = sq[q];
    }
    __syncthreads();
    int st = tid >> 7;   // 0=sum, 1=sumsq
    int c = tid & 127;
    float v = 0.f;
#pragma unroll
    for (int k = 0; k < 8; ++k) v += red[st][c][k];
    part[((size_t)c * NB + blockIdx.x) * 2 + st] = v;
}

// Finalize BN: reduce NB per-block partials -> scale/shift per channel.
template <int NB, int NBN>
__global__ __launch_bounds__(256) void bn_finish(const float* __restrict__ part,
                                                 const float* __restrict__ gamma,
                                                 const float* __restrict__ beta,
                                                 float* __restrict__ fin) {
    int c = blockIdx.x;
    int tid = threadIdx.x;
    float sm = 0.f, s2 = 0.f;
    for (int i = tid; i < NB; i += 256) {
        sm += part[((size_t)c * NB + i) * 2];
        s2 += part[((size_t)c * NB + i) * 2 + 1];
    }
    __shared__ float r0[256], r1[256];
    r0[tid] = sm; r1[tid] = s2;
    __syncthreads();
    for (int off = 128; off > 0; off >>= 1) {
        if (tid < off) { r0[tid] += r0[tid + off]; r1[tid] += r1[tid + off]; }
        __syncthreads();
    }
    if (tid == 0) {
        const float invN = 1.f / (float)NBN;
        float mean = r0[0] * invN;
        float var = r1[0] * invN - mean * mean;
        float rs = rsqrtf(var + 1e-5f);
        float scl = gamma[c] * rs;
        fin[c * 2] = scl;
        fin[c * 2 + 1] = beta[c] - mean * scl;
    }
}

// BN3 (finalized) + avgpool(2x2) + FC(128->1) + sigmoid. One wave per batch.
__global__ void head_ker(const float* __restrict__ a4, const float* __restrict__ fin3,
                         const float* __restrict__ fcw, const float* __restrict__ fcb,
                         float* __restrict__ out) {
    int b = blockIdx.x;
    int lane = threadIdx.x;  // 64
    float acc = 0.0f;
#pragma unroll
    for (int j = 0; j < 2; ++j) {
        int o = lane + 64 * j;
        float scl = fin3[o * 2];
        float sh = fin3[o * 2 + 1];
        const float* p = a4 + (b * 128 + o) * 4;
        float sv = p[0] + p[1] + p[2] + p[3];
        float pooled = fmaf(sv * 0.25f, scl, sh);
        acc = fmaf(pooled, fcw[o], acc);
    }
#pragma unroll
    for (int off = 32; off > 0; off >>= 1) acc += __shfl_down(acc, off);
    if (lane == 0) out[b] = 1.0f / (1.0f + expf(-(acc + fcb[0])));
}

extern "C" void kernel_launch(void* const* d_in, const int* in_sizes, int n_in,
                              void* d_out, int out_size, void* d_ws, size_t ws_size,
                              hipStream_t stream) {
    const float* x   = (const float*)d_in[0];
    const float* bw1 = (const float*)d_in[1];
    const float* sw1 = (const float*)d_in[2];
    const float* sc1 = (const float*)d_in[3];
    const float* bw2 = (const float*)d_in[4];
    const float* sw2 = (const float*)d_in[5];
    const float* sc2 = (const float*)d_in[6];
    const float* bw3 = (const float*)d_in[7];
    const float* sw3 = (const float*)d_in[8];
    const float* sc3 = (const float*)d_in[9];
    const float* bw4 = (const float*)d_in[10];
    const float* sw4 = (const float*)d_in[11];
    const float* sc4 = (const float*)d_in[12];
    const float* g1  = (const float*)d_in[13];
    const float* b1  = (const float*)d_in[14];
    const float* g2  = (const float*)d_in[15];
    const float* b2  = (const float*)d_in[16];
    const float* g3  = (const float*)d_in[17];
    const float* b3  = (const float*)d_in[18];
    const float* fcw = (const float*)d_in[19];
    const float* fcb = (const float*)d_in[20];

    float* ws = (float*)d_ws;
    float* a1 = ws;                    // 4194304 floats (dead after L2 -> P3)
    float* a2 = a1 + 4194304;          // 2097152 (dead after L3 -> P4)
    float* a3 = a2 + 2097152;          // 1048576
    float* a4 = a3 + 1048576;          // 262144
    unsigned short* wf1 = (unsigned short*)(a4 + 262144);  // 12288 ushorts
    unsigned short* wf2 = wf1 + 12288;      // 262144
    unsigned short* wf3 = wf2 + 262144;     // 1048576
    unsigned short* wf4 = wf3 + 1048576;    // 2097152
    float* part1 = (float*)(wf4 + 2097152); // 64*256*2   = 32768
    float* part2 = part1 + 32768;           // 128*1024*2 = 262144
    float* part3 = part2 + 262144;          // 128*256*2  = 65536
    float* fin1  = part3 + 65536;           // 64*2  = 128
    float* fin2  = fin1 + 128;              // 128*2 = 256
    float* fin3  = fin2 + 256;              // 128*2 = 256
    float* P3 = a1;                    // 4 * 8192*128 = 4194304 floats
    float* P4 = a2;                    // 8 * 2048*128 = 2097152 floats

    // weight prep: one fragment per thread (427520 frags)
    prep_all<<<1670, 256, 0, stream>>>(bw1, sw1, sc1, bw2, sw2, sc2,
                                       bw3, sw3, sc3, bw4, sw4, sc4,
                                       wf1, wf2, wf3, wf4);

    // L1: (512,3,32,32) -> (512,32,16,16), BM=256 (1 image), single phase UB=3
    kan_conv_fused<3, 32, 1, 16, 16, 4, 1, 4, 3, 3, false, 1, 1, false, 0>
        <<<512, 256, 0, stream>>>(x, wf1, nullptr, nullptr, nullptr, a1, nullptr);
    // L2: -> (512,64,8,8), BM=128 (2 images), N-split 2, UB=4 (8 phases),
    // BN1 partial-stats fused into epilogue (STATS=true)
    kan_conv_fused<32, 64, 2, 8, 8, 4, 1, 2, 32, 4, false, 1, 1, false, 0, true>
        <<<dim3(256, 2), 256, 0, stream>>>(a1, wf2, nullptr, nullptr, nullptr, a2, part1);
    bn_finish<256, 32768><<<64, 256, 0, stream>>>(part1, g1, b1, fin1);
    // L3: -> (512,128,4,4), BM=128 (8 images), N-split 2 x K-split 4x16ch,
    // UB=2, BN1 finalized (BNS=1)
    kan_conv_fused<64, 128, 2, 4, 4, 4, 1, 2, 16, 2, true, 1, 1, true, 1>
        <<<dim3(64, 8), 256, 0, stream>>>(a2, wf3, fin1, nullptr, nullptr, P3, nullptr);
    // fused reduce(P3 -> a3) + BN2 block partials (full 1024-block grid)
    reduce_bn<4, 128, 4, 4, 1024><<<1024, 256, 0, stream>>>(P3, a3, part2);
    bn_finish<1024, 8192><<<128, 256, 0, stream>>>(part2, g2, b2, fin2);
    // L4: -> (512,128,2,2), BM=64 (16 images), N-split 2 x K-split 8x16ch,
    // UB=2, BN2 finalized (BNS=1)
    kan_conv_fused<128, 128, 2, 2, 2, 4, 1, 1, 16, 2, true, 1, 1, true, 0>
        <<<dim3(32, 16), 256, 0, stream>>>(a3, wf4, fin2, nullptr, nullptr, P4, nullptr);
    // fused reduce(P4 -> a4) + BN3 block partials (full 256-block grid)
    reduce_bn<8, 128, 2, 2, 256><<<256, 256, 0, stream>>>(P4, a4, part3);
    bn_finish<256, 2048><<<128, 256, 0, stream>>>(part3, g3, b3, fin3);
    // Head: BN3 (finalized) + pool + FC + sigmoid
    head_ker<<<512, 64, 0, stream>>>(a4, fin3, fcw, fcb, (float*)d_out);
}